// Round 6
// baseline (697.255 us; speedup 1.0000x reference)
//
#include <hip/hip_runtime.h>
#include <hip/hip_bf16.h>
#include <math.h>

#define AS1 __attribute__((address_space(1)))
#define AS3 __attribute__((address_space(3)))

typedef __bf16  bf16x8 __attribute__((ext_vector_type(8)));
typedef float   f32x4  __attribute__((ext_vector_type(4)));
typedef __hip_bfloat16 bf16;

__device__ __forceinline__ void gload_lds16(const void* g, void* l) {
  __builtin_amdgcn_global_load_lds((const AS1 void*)g, (AS3 void*)l, 16, 0, 0);
}

// ---------------- weight conversion f32 -> bf16 ----------------
__global__ __launch_bounds__(256) void k_conv_weights(
    const float* __restrict__ qkvw, const float* __restrict__ projw,
    const float* __restrict__ w1, const float* __restrict__ w2,
    bf16* __restrict__ dst)
{
  int i = blockIdx.x * 256 + threadIdx.x;   // grid covers exactly 786432
  float v;
  if (i < 196608)       v = qkvw[i];
  else if (i < 262144)  v = projw[i - 196608];
  else if (i < 524288)  v = w1[i - 262144];
  else                  v = w2[i - 524288];
  dst[i] = __float2bfloat16(v);
}

// ---------------- rel-pos bias table: btab[h][n][m] ----------------
__global__ __launch_bounds__(256) void k_build_btab(
    const float* __restrict__ rel_bias, float* __restrict__ btab)
{
  int i = blockIdx.x * 256 + threadIdx.x;   // 32768
  int h = i >> 12, r = i & 4095, n = r >> 6, m = r & 63;
  int idx = ((n >> 3) - (m >> 3) + 7) * 15 + ((n & 7) - (m & 7) + 7);
  btab[i] = rel_bias[idx * 8 + h];
}

// ---------------- LN1 + roll(-4,-4) + window partition, f32 -> bf16 ----------------
__global__ __launch_bounds__(256) void k_ln1_window(
    const float* __restrict__ x, const float* __restrict__ sc,
    const float* __restrict__ bi, bf16* __restrict__ hout)
{
  int t = blockIdx.x * 4 + (threadIdx.x >> 6);
  int lane = threadIdx.x & 63;
  int win = t >> 6, nn = t & 63;
  int b = win >> 6, ww = win & 63;
  int ry = ((ww >> 3) << 3) + (nn >> 3);
  int rx = ((ww & 7) << 3) + (nn & 7);
  int sy = (ry + 4) & 63, sx = (rx + 4) & 63;
  const float* src = x + ((size_t)(((b << 6) + sy) << 6) + sx) * 256;
  f32x4 v = *(const f32x4*)(src + lane * 4);
  float s = v[0] + v[1] + v[2] + v[3];
  #pragma unroll
  for (int o = 1; o < 64; o <<= 1) s += __shfl_xor(s, o);
  float mu = s * (1.0f / 256.0f);
  float d0 = v[0]-mu, d1 = v[1]-mu, d2 = v[2]-mu, d3 = v[3]-mu;
  float q = d0*d0 + d1*d1 + d2*d2 + d3*d3;
  #pragma unroll
  for (int o = 1; o < 64; o <<= 1) q += __shfl_xor(q, o);
  float rstd = rsqrtf(q * (1.0f / 256.0f) + 1e-5f);
  int c = lane * 4;
  union { bf16 h[4]; uint2 u; } pk;
  pk.h[0] = __float2bfloat16(d0 * rstd * sc[c+0] + bi[c+0]);
  pk.h[1] = __float2bfloat16(d1 * rstd * sc[c+1] + bi[c+1]);
  pk.h[2] = __float2bfloat16(d2 * rstd * sc[c+2] + bi[c+2]);
  pk.h[3] = __float2bfloat16(d3 * rstd * sc[c+3] + bi[c+3]);
  *(uint2*)(hout + (size_t)t * 256 + c) = pk.u;
}

// ---------------- LN2 (pixel-major), f32 -> bf16 ----------------
__global__ __launch_bounds__(256) void k_ln2(
    const float* __restrict__ x1, const float* __restrict__ sc,
    const float* __restrict__ bi, bf16* __restrict__ out)
{
  int t = blockIdx.x * 4 + (threadIdx.x >> 6);
  int lane = threadIdx.x & 63;
  const float* src = x1 + (size_t)t * 256;
  f32x4 v = *(const f32x4*)(src + lane * 4);
  float s = v[0] + v[1] + v[2] + v[3];
  #pragma unroll
  for (int o = 1; o < 64; o <<= 1) s += __shfl_xor(s, o);
  float mu = s * (1.0f / 256.0f);
  float d0 = v[0]-mu, d1 = v[1]-mu, d2 = v[2]-mu, d3 = v[3]-mu;
  float q = d0*d0 + d1*d1 + d2*d2 + d3*d3;
  #pragma unroll
  for (int o = 1; o < 64; o <<= 1) q += __shfl_xor(q, o);
  float rstd = rsqrtf(q * (1.0f / 256.0f) + 1e-5f);
  int c = lane * 4;
  union { bf16 h[4]; uint2 u; } pk;
  pk.h[0] = __float2bfloat16(d0 * rstd * sc[c+0] + bi[c+0]);
  pk.h[1] = __float2bfloat16(d1 * rstd * sc[c+1] + bi[c+1]);
  pk.h[2] = __float2bfloat16(d2 * rstd * sc[c+2] + bi[c+2]);
  pk.h[3] = __float2bfloat16(d3 * rstd * sc[c+3] + bi[c+3]);
  *(uint2*)(out + (size_t)t * 256 + c) = pk.u;
}

// ============ W-resident streaming-M GEMM (K=256), no LDS, no barriers ============
// Each wave owns 16 output cols; its W-slice (16 cols x 256 K) lives in 8 bf16x8
// frags = 32 VGPR, loaded ONCE. Loop streams 32 rows/iter: 16 A-frag loads ->
// 16 MFMA -> vector stores. acc = mfma(wf, af): lane holds row (r+l15),
// cols (colBase + lh*4 .. +3).
// EPI 0: bf16 store | EPI 1: GELU -> bf16 | EPI 2: proj remap + resid, f32
template<int EPI>
__global__ __launch_bounds__(256) void k_gemm_wres(
    const bf16* __restrict__ A, const bf16* __restrict__ Bw,
    const float* __restrict__ bias,
    float* __restrict__ Cf, bf16* __restrict__ Cb,
    const float* __restrict__ resid, int N, int NCG, int ITERS)
{
  const int tid = threadIdx.x;
  const int lane = tid & 63, l15 = lane & 15, lh = lane >> 4;
  const int wv = tid >> 6;
  const int cg = blockIdx.x % NCG;
  const int mBase = (blockIdx.x / NCG) * (ITERS * 32);
  const int colBase = cg * 64 + wv * 16;

  // ---- resident W fragments (16 cols x 256 K = 32 VGPR) ----
  bf16x8 wf0, wf1, wf2, wf3, wf4, wf5, wf6, wf7;
  {
    const bf16* wp = Bw + (size_t)(colBase + l15) * 256 + lh * 8;
    wf0 = *(const bf16x8*)(wp +   0); wf1 = *(const bf16x8*)(wp +  32);
    wf2 = *(const bf16x8*)(wp +  64); wf3 = *(const bf16x8*)(wp +  96);
    wf4 = *(const bf16x8*)(wp + 128); wf5 = *(const bf16x8*)(wp + 160);
    wf6 = *(const bf16x8*)(wp + 192); wf7 = *(const bf16x8*)(wp + 224);
  }
  const int colb = colBase + lh * 4;
  const f32x4 b4 = *(const f32x4*)(bias + colb);

  for (int it = 0; it < ITERS; ++it) {
    const int r0 = mBase + it * 32;
    const bf16* ap = A + (size_t)(r0 + l15) * 256 + lh * 8;
    bf16x8 a00 = *(const bf16x8*)(ap +   0);
    bf16x8 a01 = *(const bf16x8*)(ap +  32);
    bf16x8 a02 = *(const bf16x8*)(ap +  64);
    bf16x8 a03 = *(const bf16x8*)(ap +  96);
    bf16x8 a04 = *(const bf16x8*)(ap + 128);
    bf16x8 a05 = *(const bf16x8*)(ap + 160);
    bf16x8 a06 = *(const bf16x8*)(ap + 192);
    bf16x8 a07 = *(const bf16x8*)(ap + 224);
    const bf16* ap1 = ap + 4096;           // +16 rows
    bf16x8 a10 = *(const bf16x8*)(ap1 +   0);
    bf16x8 a11 = *(const bf16x8*)(ap1 +  32);
    bf16x8 a12 = *(const bf16x8*)(ap1 +  64);
    bf16x8 a13 = *(const bf16x8*)(ap1 +  96);
    bf16x8 a14 = *(const bf16x8*)(ap1 + 128);
    bf16x8 a15 = *(const bf16x8*)(ap1 + 160);
    bf16x8 a16 = *(const bf16x8*)(ap1 + 192);
    bf16x8 a17 = *(const bf16x8*)(ap1 + 224);

    f32x4 acc0 = (f32x4){0.f,0.f,0.f,0.f};
    f32x4 acc1 = (f32x4){0.f,0.f,0.f,0.f};
    acc0 = __builtin_amdgcn_mfma_f32_16x16x32_bf16(wf0, a00, acc0, 0, 0, 0);
    acc1 = __builtin_amdgcn_mfma_f32_16x16x32_bf16(wf0, a10, acc1, 0, 0, 0);
    acc0 = __builtin_amdgcn_mfma_f32_16x16x32_bf16(wf1, a01, acc0, 0, 0, 0);
    acc1 = __builtin_amdgcn_mfma_f32_16x16x32_bf16(wf1, a11, acc1, 0, 0, 0);
    acc0 = __builtin_amdgcn_mfma_f32_16x16x32_bf16(wf2, a02, acc0, 0, 0, 0);
    acc1 = __builtin_amdgcn_mfma_f32_16x16x32_bf16(wf2, a12, acc1, 0, 0, 0);
    acc0 = __builtin_amdgcn_mfma_f32_16x16x32_bf16(wf3, a03, acc0, 0, 0, 0);
    acc1 = __builtin_amdgcn_mfma_f32_16x16x32_bf16(wf3, a13, acc1, 0, 0, 0);
    acc0 = __builtin_amdgcn_mfma_f32_16x16x32_bf16(wf4, a04, acc0, 0, 0, 0);
    acc1 = __builtin_amdgcn_mfma_f32_16x16x32_bf16(wf4, a14, acc1, 0, 0, 0);
    acc0 = __builtin_amdgcn_mfma_f32_16x16x32_bf16(wf5, a05, acc0, 0, 0, 0);
    acc1 = __builtin_amdgcn_mfma_f32_16x16x32_bf16(wf5, a15, acc1, 0, 0, 0);
    acc0 = __builtin_amdgcn_mfma_f32_16x16x32_bf16(wf6, a06, acc0, 0, 0, 0);
    acc1 = __builtin_amdgcn_mfma_f32_16x16x32_bf16(wf6, a16, acc1, 0, 0, 0);
    acc0 = __builtin_amdgcn_mfma_f32_16x16x32_bf16(wf7, a07, acc0, 0, 0, 0);
    acc1 = __builtin_amdgcn_mfma_f32_16x16x32_bf16(wf7, a17, acc1, 0, 0, 0);

    // ---- epilogue for these 32 rows ----
    #pragma unroll
    for (int m = 0; m < 2; ++m) {
      const f32x4 av = (m == 0) ? acc0 : acc1;
      const int row = r0 + m * 16 + l15;
      size_t rowAddr;
      if (EPI == 2) {
        int win = row >> 6, nn = row & 63;
        int b = win >> 6, ww = win & 63;
        int ry = ((ww >> 3) << 3) + (nn >> 3);
        int rx = ((ww & 7) << 3) + (nn & 7);
        int fy = (ry + 4) & 63, fx = (rx + 4) & 63;
        rowAddr = ((size_t)(((b << 6) + fy) << 6) + fx) * 256;
      } else {
        rowAddr = (size_t)row * N;
      }
      if (EPI == 0) {
        union { bf16 h[4]; uint2 u; } pk;
        #pragma unroll
        for (int j = 0; j < 4; ++j) pk.h[j] = __float2bfloat16(av[j] + b4[j]);
        *(uint2*)(Cb + rowAddr + colb) = pk.u;
      } else if (EPI == 1) {
        union { bf16 h[4]; uint2 u; } pk;
        #pragma unroll
        for (int j = 0; j < 4; ++j) {
          float v = av[j] + b4[j];
          float w = fmaf(v * v, 0.1029434f, 2.3022083f);   // ln2-folded tanh-GELU
          float e = __builtin_amdgcn_exp2f(-v * w);
          pk.h[j] = __float2bfloat16(v * __builtin_amdgcn_rcpf(1.0f + e));
        }
        *(uint2*)(Cb + rowAddr + colb) = pk.u;
      } else {
        const f32x4 r4 = *(const f32x4*)(resid + rowAddr + colb);
        f32x4 o4;
        #pragma unroll
        for (int j = 0; j < 4; ++j) o4[j] = av[j] + b4[j] + r4[j];
        *(f32x4*)(Cf + rowAddr + colb) = o4;
      }
    }
  }
}

// ---------------- classic tiled GEMM (for MLP2, K=1024): C = A@Bw^T ----------------
// Cf[addr] += val + bias (residual already in Cf), f32
#define BM 128
#define BN 128
#define BKK 64

__global__ __launch_bounds__(256) void k_gemm_bt3(
    const bf16* __restrict__ A, const bf16* __restrict__ Bw,
    const float* __restrict__ bias, float* __restrict__ Cf,
    int M, int N, int K)
{
  __shared__ __align__(16) char lds[BM*BKK*2 + BN*BKK*2];
  char* ldsA = lds;
  char* ldsB = lds + BM*BKK*2;

  const int tid = threadIdx.x;
  const int wid = tid >> 6;
  const int lane = tid & 63;
  const int l15 = lane & 15, lh = lane >> 4;
  const int rowBase = blockIdx.y * BM;
  const int colBase = blockIdx.x * BN;
  const int wr = (wid >> 1) * 64;
  const int wc = (wid & 1) * 64;

  f32x4 acc[4][4];
  #pragma unroll
  for (int i = 0; i < 4; ++i)
    #pragma unroll
    for (int j = 0; j < 4; ++j) acc[i][j] = (f32x4){0.f,0.f,0.f,0.f};

  for (int k0 = 0; k0 < K; k0 += BKK) {
    #pragma unroll
    for (int i = 0; i < 4; ++i) {
      int chunk = i * 4 + wid;
      int off = (chunk * 64 + lane) * 16;
      int r = off >> 7, cb = off & 127;
      int csw = cb ^ ((r & 7) << 4);
      gload_lds16((const char*)(A + (size_t)(rowBase + r) * K + k0) + csw, ldsA + chunk * 1024);
      gload_lds16((const char*)(Bw + (size_t)(colBase + r) * K + k0) + csw, ldsB + chunk * 1024);
    }
    __syncthreads();
    #pragma unroll
    for (int kk = 0; kk < BKK / 32; ++kk) {
      bf16x8 af[4], bfr[4];
      int kb = kk * 64 + lh * 16;
      #pragma unroll
      for (int m = 0; m < 4; ++m) {
        int rA = wr + m * 16 + l15;
        af[m] = *(const bf16x8*)(ldsA + rA * 128 + (kb ^ ((rA & 7) << 4)));
        int rB = wc + m * 16 + l15;
        bfr[m] = *(const bf16x8*)(ldsB + rB * 128 + (kb ^ ((rB & 7) << 4)));
      }
      #pragma unroll
      for (int m = 0; m < 4; ++m)
        #pragma unroll
        for (int n = 0; n < 4; ++n)
          acc[m][n] = __builtin_amdgcn_mfma_f32_16x16x32_bf16(bfr[n], af[m], acc[m][n], 0, 0, 0);
    }
    __syncthreads();
  }

  #pragma unroll
  for (int m = 0; m < 4; ++m) {
    size_t rowAddr = (size_t)(rowBase + wr + m * 16 + l15) * N;
    #pragma unroll
    for (int n = 0; n < 4; ++n) {
      const int colb = colBase + wc + n * 16 + lh * 4;
      const f32x4 b4 = *(const f32x4*)(bias + colb);
      f32x4* p = (f32x4*)(Cf + rowAddr + colb);
      f32x4 c = *p;
      #pragma unroll
      for (int j = 0; j < 4; ++j) c[j] += acc[m][n][j] + b4[j];
      *p = c;
    }
  }
}

// ---------------- attention: 1 wave per (window, head) ----------------
__global__ __launch_bounds__(256) void k_attn(
    const bf16* __restrict__ qkv, const float* __restrict__ btab,
    bf16* __restrict__ outp)
{
  __shared__ __align__(16) char smem[71680];
  float* sb = (float*)smem;                        // 64*64 f32 bias for this head
  const int tid = threadIdx.x, wid = tid >> 6, lane = tid & 63;
  const int l15 = lane & 15, lh = lane >> 4;
  const int h = blockIdx.x >> 8;
  const int win = ((blockIdx.x & 255) << 2) + wid;
  const int tb = win << 6;
  char* plw = smem + 16384 + wid * 9216;           // P: 64 rows x 144B
  char* vtw = smem + 16384 + 36864 + wid * 4608;   // Vt: 32 rows x 144B

  for (int i = tid; i < 4096; i += 256) sb[i] = btab[(h << 12) + i];
  __syncthreads();

  bf16x8 qf[4], kf[4];
  #pragma unroll
  for (int m = 0; m < 4; ++m) {
    size_t base = (size_t)(tb + m * 16 + l15) * 768 + h * 32 + lh * 8;
    qf[m] = *(const bf16x8*)(qkv + base);
    kf[m] = *(const bf16x8*)(qkv + base + 256);
  }
  f32x4 s[4][4];
  #pragma unroll
  for (int i = 0; i < 4; ++i)
    #pragma unroll
    for (int j = 0; j < 4; ++j) {
      s[i][j] = (f32x4){0.f,0.f,0.f,0.f};
      s[i][j] = __builtin_amdgcn_mfma_f32_16x16x32_bf16(qf[i], kf[j], s[i][j], 0, 0, 0);
    }

  #pragma unroll
  for (int it = 0; it < 32; ++it) {
    int idx = it * 64 + lane;
    int m = idx >> 5, d = idx & 31;
    bf16 vv = qkv[(size_t)(tb + m) * 768 + 512 + h * 32 + d];
    *(bf16*)(vtw + d * 144 + m * 2) = vv;
  }

  int ww = win & 63, wi = ww >> 3, wj = ww & 7;
  int labm[4];
  #pragma unroll
  for (int jf = 0; jf < 4; ++jf) {
    int m = jf * 16 + l15;
    int yy = wi * 8 + (m >> 3), xx = wj * 8 + (m & 7);
    labm[jf] = (yy < 56 ? 0 : (yy < 60 ? 1 : 2)) * 3 + (xx < 56 ? 0 : (xx < 60 ? 1 : 2));
  }
  float rsum[4][4];
  const float scale = 0.17677669529663687f;  // 1/sqrt(32)
  #pragma unroll
  for (int i = 0; i < 4; ++i) {
    #pragma unroll
    for (int j = 0; j < 4; ++j) {
      int n = i * 16 + lh * 4 + j;
      int yy = wi * 8 + (n >> 3), xx = wj * 8 + (n & 7);
      int labn = (yy < 56 ? 0 : (yy < 60 ? 1 : 2)) * 3 + (xx < 56 ? 0 : (xx < 60 ? 1 : 2));
      float vals[4]; float mx = -1e30f;
      #pragma unroll
      for (int jf = 0; jf < 4; ++jf) {
        int m = jf * 16 + l15;
        float v = s[i][jf][j] * scale + sb[(n << 6) + m];
        if (labn != labm[jf]) v -= 100.0f;
        vals[jf] = v; mx = fmaxf(mx, v);
      }
      #pragma unroll
      for (int o = 1; o < 16; o <<= 1) mx = fmaxf(mx, __shfl_xor(mx, o));
      float sum = 0.0f;
      #pragma unroll
      for (int jf = 0; jf < 4; ++jf) {
        float e = __expf(vals[jf] - mx);
        sum += e;
        *(bf16*)(plw + n * 144 + (jf * 16 + l15) * 2) = __float2bfloat16(e);
      }
      #pragma unroll
      for (int o = 1; o < 16; o <<= 1) sum += __shfl_xor(sum, o);
      rsum[i][j] = sum;
    }
  }
  __syncthreads();

  f32x4 o[4][2];
  #pragma unroll
  for (int i = 0; i < 4; ++i) { o[i][0] = (f32x4){0.f,0.f,0.f,0.f}; o[i][1] = (f32x4){0.f,0.f,0.f,0.f}; }
  #pragma unroll
  for (int kk = 0; kk < 2; ++kk) {
    bf16x8 pf[4], vf[2];
    #pragma unroll
    for (int i = 0; i < 4; ++i)
      pf[i] = *(const bf16x8*)(plw + (i * 16 + l15) * 144 + kk * 64 + lh * 16);
    #pragma unroll
    for (int df = 0; df < 2; ++df)
      vf[df] = *(const bf16x8*)(vtw + (df * 16 + l15) * 144 + kk * 64 + lh * 16);
    #pragma unroll
    for (int i = 0; i < 4; ++i)
      #pragma unroll
      for (int df = 0; df < 2; ++df)
        o[i][df] = __builtin_amdgcn_mfma_f32_16x16x32_bf16(pf[i], vf[df], o[i][df], 0, 0, 0);
  }
  #pragma unroll
  for (int i = 0; i < 4; ++i)
    #pragma unroll
    for (int df = 0; df < 2; ++df)
      #pragma unroll
      for (int j = 0; j < 4; ++j) {
        int n = i * 16 + lh * 4 + j;
        int d = df * 16 + l15;
        float v = o[i][df][j] / rsum[i][j];
        outp[(size_t)(tb + n) * 256 + h * 32 + d] = __float2bfloat16(v);
      }
}

// ---------------- launch ----------------
extern "C" void kernel_launch(void* const* d_in, const int* in_sizes, int n_in,
                              void* d_out, int out_size, void* d_ws, size_t ws_size,
                              hipStream_t stream) {
  (void)in_sizes; (void)n_in; (void)out_size; (void)ws_size;
  const float* x      = (const float*)d_in[0];
  const float* ln1_s  = (const float*)d_in[1];
  const float* ln1_b  = (const float*)d_in[2];
  const float* qkv_w  = (const float*)d_in[3];
  const float* qkv_b  = (const float*)d_in[4];
  const float* proj_w = (const float*)d_in[5];
  const float* proj_b = (const float*)d_in[6];
  const float* rel_b  = (const float*)d_in[7];
  const float* ln2_s  = (const float*)d_in[8];
  const float* ln2_b  = (const float*)d_in[9];
  const float* w1     = (const float*)d_in[10];
  const float* b1     = (const float*)d_in[11];
  const float* w2     = (const float*)d_in[12];
  const float* b2     = (const float*)d_in[13];

  char* ws = (char*)d_ws;
  bf16*  wqkv  = (bf16*)(ws + 0);               // 196608 el
  bf16*  wproj = wqkv + 196608;                 // 65536 el
  bf16*  wm1   = wqkv + 262144;                 // 262144 el
  bf16*  wm2   = wqkv + 524288;                 // 262144 el
  float* btab  = (float*)(ws + 1572864);        // 32768 f32
  bf16*  hbuf  = (bf16*)(ws + 2097152);         // 65536x256 (34MB..)
  bf16*  qkvb  = (bf16*)(ws + 35651584);        // 65536x768 (34MB..134MB)
  bf16*  attnb = (bf16*)(ws + 136314880);       // 65536x256 (130MB..163MB)
  bf16*  ln2buf = hbuf;                         // reuse (h dead after QKV gemm)
  bf16*  actb  = qkvb;                          // 65536x1024 (qkv+attn dead after proj)
  float* x1    = (float*)d_out;                 // residual lives in d_out

  k_conv_weights<<<3072, 256, 0, stream>>>(qkv_w, proj_w, w1, w2, wqkv);
  k_build_btab<<<128, 256, 0, stream>>>(rel_b, btab);
  k_ln1_window<<<16384, 256, 0, stream>>>(x, ln1_s, ln1_b, hbuf);
  // QKV: N=768, 12 col-groups x 128 M-chunks (512 rows each)
  k_gemm_wres<0><<<1536, 256, 0, stream>>>(hbuf, wqkv, qkv_b, nullptr, qkvb, nullptr, 768, 12, 16);
  k_attn<<<2048, 256, 0, stream>>>(qkvb, btab, attnb);
  // proj: N=256, 4 col-groups x 256 M-chunks (256 rows each)
  k_gemm_wres<2><<<1024, 256, 0, stream>>>(attnb, wproj, proj_b, x1, nullptr, x, 256, 4, 8);
  k_ln2<<<16384, 256, 0, stream>>>(x1, ln2_s, ln2_b, ln2buf);
  // MLP1: N=1024, 16 col-groups x 128 M-chunks (512 rows each)
  k_gemm_wres<1><<<2048, 256, 0, stream>>>(ln2buf, wm1, b1, nullptr, actb, nullptr, 1024, 16, 16);
  k_gemm_bt3<<<dim3(2, 512), 256, 0, stream>>>(actb, wm2, b2, x1, 65536, 256, 1024);
}

// Round 7
// 394.508 us; speedup vs baseline: 1.7674x; 1.7674x over previous
//
#include <hip/hip_runtime.h>
#include <hip/hip_bf16.h>
#include <math.h>

#define AS1 __attribute__((address_space(1)))
#define AS3 __attribute__((address_space(3)))

typedef __bf16  bf16x8 __attribute__((ext_vector_type(8)));
typedef float   f32x4  __attribute__((ext_vector_type(4)));
typedef __hip_bfloat16 bf16;

__device__ __forceinline__ void gload_lds16(const void* g, void* l) {
  __builtin_amdgcn_global_load_lds((const AS1 void*)g, (AS3 void*)l, 16, 0, 0);
}

// ---------------- weight conversion f32 -> bf16 ----------------
__global__ __launch_bounds__(256) void k_conv_weights(
    const float* __restrict__ qkvw, const float* __restrict__ projw,
    const float* __restrict__ w1, const float* __restrict__ w2,
    bf16* __restrict__ dst)
{
  int i = blockIdx.x * 256 + threadIdx.x;   // grid covers exactly 786432
  float v;
  if (i < 196608)       v = qkvw[i];
  else if (i < 262144)  v = projw[i - 196608];
  else if (i < 524288)  v = w1[i - 262144];
  else                  v = w2[i - 524288];
  dst[i] = __float2bfloat16(v);
}

// ---------------- rel-pos bias table: btab[h][n][m] ----------------
__global__ __launch_bounds__(256) void k_build_btab(
    const float* __restrict__ rel_bias, float* __restrict__ btab)
{
  int i = blockIdx.x * 256 + threadIdx.x;   // 32768
  int h = i >> 12, r = i & 4095, n = r >> 6, m = r & 63;
  int idx = ((n >> 3) - (m >> 3) + 7) * 15 + ((n & 7) - (m & 7) + 7);
  btab[i] = rel_bias[idx * 8 + h];
}

// ---------------- LN1 + roll(-4,-4) + window partition, f32 -> bf16 ----------------
__global__ __launch_bounds__(256) void k_ln1_window(
    const float* __restrict__ x, const float* __restrict__ sc,
    const float* __restrict__ bi, bf16* __restrict__ hout)
{
  int t = blockIdx.x * 4 + (threadIdx.x >> 6);
  int lane = threadIdx.x & 63;
  int win = t >> 6, nn = t & 63;
  int b = win >> 6, ww = win & 63;
  int ry = ((ww >> 3) << 3) + (nn >> 3);
  int rx = ((ww & 7) << 3) + (nn & 7);
  int sy = (ry + 4) & 63, sx = (rx + 4) & 63;
  const float* src = x + ((size_t)(((b << 6) + sy) << 6) + sx) * 256;
  f32x4 v = *(const f32x4*)(src + lane * 4);
  float s = v[0] + v[1] + v[2] + v[3];
  #pragma unroll
  for (int o = 1; o < 64; o <<= 1) s += __shfl_xor(s, o);
  float mu = s * (1.0f / 256.0f);
  float d0 = v[0]-mu, d1 = v[1]-mu, d2 = v[2]-mu, d3 = v[3]-mu;
  float q = d0*d0 + d1*d1 + d2*d2 + d3*d3;
  #pragma unroll
  for (int o = 1; o < 64; o <<= 1) q += __shfl_xor(q, o);
  float rstd = rsqrtf(q * (1.0f / 256.0f) + 1e-5f);
  int c = lane * 4;
  union { bf16 h[4]; uint2 u; } pk;
  pk.h[0] = __float2bfloat16(d0 * rstd * sc[c+0] + bi[c+0]);
  pk.h[1] = __float2bfloat16(d1 * rstd * sc[c+1] + bi[c+1]);
  pk.h[2] = __float2bfloat16(d2 * rstd * sc[c+2] + bi[c+2]);
  pk.h[3] = __float2bfloat16(d3 * rstd * sc[c+3] + bi[c+3]);
  *(uint2*)(hout + (size_t)t * 256 + c) = pk.u;
}

// ---------------- LN2 (pixel-major), f32 -> bf16 ----------------
__global__ __launch_bounds__(256) void k_ln2(
    const float* __restrict__ x1, const float* __restrict__ sc,
    const float* __restrict__ bi, bf16* __restrict__ out)
{
  int t = blockIdx.x * 4 + (threadIdx.x >> 6);
  int lane = threadIdx.x & 63;
  const float* src = x1 + (size_t)t * 256;
  f32x4 v = *(const f32x4*)(src + lane * 4);
  float s = v[0] + v[1] + v[2] + v[3];
  #pragma unroll
  for (int o = 1; o < 64; o <<= 1) s += __shfl_xor(s, o);
  float mu = s * (1.0f / 256.0f);
  float d0 = v[0]-mu, d1 = v[1]-mu, d2 = v[2]-mu, d3 = v[3]-mu;
  float q = d0*d0 + d1*d1 + d2*d2 + d3*d3;
  #pragma unroll
  for (int o = 1; o < 64; o <<= 1) q += __shfl_xor(q, o);
  float rstd = rsqrtf(q * (1.0f / 256.0f) + 1e-5f);
  int c = lane * 4;
  union { bf16 h[4]; uint2 u; } pk;
  pk.h[0] = __float2bfloat16(d0 * rstd * sc[c+0] + bi[c+0]);
  pk.h[1] = __float2bfloat16(d1 * rstd * sc[c+1] + bi[c+1]);
  pk.h[2] = __float2bfloat16(d2 * rstd * sc[c+2] + bi[c+2]);
  pk.h[3] = __float2bfloat16(d3 * rstd * sc[c+3] + bi[c+3]);
  *(uint2*)(out + (size_t)t * 256 + c) = pk.u;
}

// ============ A-resident N-streaming GEMM (K=256), counted-vmcnt pipeline ============
// Block: 64 rows; per wave 32 rows full-K A in regs (af[2][8], 64 VGPR, held by
// __launch_bounds__(256,3)). N streamed in 32-col chunks; B-chunk 16KB staged via
// global_load_lds into a 3-buffer ring. Raw s_barrier + counted vmcnt: loads for
// chunks c+1, c+2 stay in flight across barriers (never drain to 0 in the loop).
// EPI 0: bf16 store | EPI 1: GELU -> bf16 | EPI 2: proj remap + resid, f32
template<int EPI>
__global__ __launch_bounds__(256, 3) void k_pipe_ar(
    const bf16* __restrict__ A, const bf16* __restrict__ Bw,
    const float* __restrict__ bias,
    float* __restrict__ Cf, bf16* __restrict__ Cb,
    const float* __restrict__ resid, int N)
{
  __shared__ __align__(16) char lds[49152];   // 3 x 16KB ring

  const int tid = threadIdx.x;
  const int wid = tid >> 6;
  const int lane = tid & 63;
  const int l15 = lane & 15, lh = lane >> 4;
  const int wr = (wid >> 1) * 32;       // row half within 64-row block
  const int wn = (wid & 1) * 16;        // col half within 32-col chunk
  const int rowBase = blockIdx.x * 64;
  const int NC = N >> 5;

  // ---- stage helper: chunk c -> buf[c%3], source pre-swizzled ----
  auto stage = [&](int c) {
    char* dst = lds + (c % 3) * 16384;
    const char* srcB = (const char*)Bw + (size_t)c * 32 * 512;
    #pragma unroll
    for (int i = 0; i < 4; ++i) {
      int off = (i * 256 + tid) * 16;
      int r = off >> 9, cb = off & 511;
      int csw = cb ^ ((r & 7) << 4);
      gload_lds16(srcB + (size_t)r * 512 + csw, dst + off);
    }
  };

  // ---- one-time A fragment load (32 rows x K=256 per wave) ----
  bf16x8 af[2][8];
  {
    const bf16* a0 = A + (size_t)(rowBase + wr + l15) * 256 + lh * 8;
    #pragma unroll
    for (int kk = 0; kk < 8; ++kk) {
      af[0][kk] = *(const bf16x8*)(a0 + kk * 32);
      af[1][kk] = *(const bf16x8*)(a0 + 4096 + kk * 32);   // +16 rows
    }
  }

  // ---- store row addresses ----
  size_t rowAddr[2];
  #pragma unroll
  for (int m = 0; m < 2; ++m) {
    int row = rowBase + wr + m * 16 + l15;
    if (EPI == 2) {
      int win = row >> 6, nn = row & 63;
      int b = win >> 6, ww = win & 63;
      int ry = ((ww >> 3) << 3) + (nn >> 3);
      int rx = ((ww & 7) << 3) + (nn & 7);
      int fy = (ry + 4) & 63, fx = (rx + 4) & 63;
      rowAddr[m] = ((size_t)(((b << 6) + fy) << 6) + fx) * 256;
    } else {
      rowAddr[m] = (size_t)row * N;
    }
  }

  // ---- prologue: stage chunks 0,1; ensure stage(0) done (af also older) ----
  stage(0);
  stage(1);
  asm volatile("s_waitcnt vmcnt(4)" ::: "memory");   // younger-than-stage(0) = stage(1)=4
  __builtin_amdgcn_sched_barrier(0);

  for (int c = 0; c < NC; ++c) {
    __builtin_amdgcn_s_barrier();                    // all waves: stage(c) visible
    __builtin_amdgcn_sched_barrier(0);

    if (c + 2 < NC) stage(c + 2);                    // 4 loads, fly during compute

    const int colb = c * 32 + wn + lh * 4;
    const f32x4 b4 = *(const f32x4*)(bias + colb);   // 1 load
    f32x4 r40, r41;
    if (EPI == 2) {                                  // 2 loads
      r40 = *(const f32x4*)(resid + rowAddr[0] + colb);
      r41 = *(const f32x4*)(resid + rowAddr[1] + colb);
    }

    const char* buf = lds + (c % 3) * 16384;
    const int rB = wn + l15;
    const char* brow = buf + rB * 512;
    const int bxor = (rB & 7) << 4;

    f32x4 acc0 = (f32x4){0.f,0.f,0.f,0.f};
    f32x4 acc1 = (f32x4){0.f,0.f,0.f,0.f};
    #pragma unroll
    for (int kk = 0; kk < 8; ++kk) {
      bf16x8 wf = *(const bf16x8*)(brow + ((kk * 64 + lh * 16) ^ bxor));
      acc0 = __builtin_amdgcn_mfma_f32_16x16x32_bf16(wf, af[0][kk], acc0, 0, 0, 0);
      acc1 = __builtin_amdgcn_mfma_f32_16x16x32_bf16(wf, af[1][kk], acc1, 0, 0, 0);
    }

    // epilogue: 2 stores
    if (EPI == 0) {
      union { bf16 h[4]; uint2 u; } p0, p1;
      #pragma unroll
      for (int j = 0; j < 4; ++j) {
        p0.h[j] = __float2bfloat16(acc0[j] + b4[j]);
        p1.h[j] = __float2bfloat16(acc1[j] + b4[j]);
      }
      *(uint2*)(Cb + rowAddr[0] + colb) = p0.u;
      *(uint2*)(Cb + rowAddr[1] + colb) = p1.u;
    } else if (EPI == 1) {
      union { bf16 h[4]; uint2 u; } p0, p1;
      #pragma unroll
      for (int j = 0; j < 4; ++j) {
        float v = acc0[j] + b4[j];
        float w = fmaf(v * v, 0.1029434f, 2.3022083f);   // ln2-folded tanh-GELU
        float e = __builtin_amdgcn_exp2f(-v * w);
        p0.h[j] = __float2bfloat16(v * __builtin_amdgcn_rcpf(1.0f + e));
        v = acc1[j] + b4[j];
        w = fmaf(v * v, 0.1029434f, 2.3022083f);
        e = __builtin_amdgcn_exp2f(-v * w);
        p1.h[j] = __float2bfloat16(v * __builtin_amdgcn_rcpf(1.0f + e));
      }
      *(uint2*)(Cb + rowAddr[0] + colb) = p0.u;
      *(uint2*)(Cb + rowAddr[1] + colb) = p1.u;
    } else {
      f32x4 o0, o1;
      #pragma unroll
      for (int j = 0; j < 4; ++j) {
        o0[j] = acc0[j] + b4[j] + r40[j];
        o1[j] = acc1[j] + b4[j] + r41[j];
      }
      *(f32x4*)(Cf + rowAddr[0] + colb) = o0;
      *(f32x4*)(Cf + rowAddr[1] + colb) = o1;
    }

    // ensure stage(c+1) complete before next barrier.
    // younger ops: stage(c+2)=4 + bias=1 + stores=2 (+resid=2 for EPI2)
    if (EPI == 2) { asm volatile("s_waitcnt vmcnt(9)" ::: "memory"); }
    else         { asm volatile("s_waitcnt vmcnt(7)" ::: "memory"); }
    __builtin_amdgcn_sched_barrier(0);
  }
}

// ============ MLP2 pipelined GEMM: x1 += act @ W2^T + b2 (K=1024, N=256) ============
// BM=128 rows/block, full N=256 in acc[4][8]; BKK=32; 3-buf ring (A 8KB + B 16KB);
// counted vmcnt(6) = stage(t+2)'s loads; raw barriers. A streamed from HBM once.
__global__ __launch_bounds__(256, 2) void k_pipe_bt(
    const bf16* __restrict__ A, const bf16* __restrict__ Bw,
    const float* __restrict__ bias, float* __restrict__ Cf)
{
  __shared__ __align__(16) char lds[73728];   // 3 x (8KB A + 16KB B)

  const int tid = threadIdx.x;
  const int wid = tid >> 6;
  const int lane = tid & 63;
  const int l15 = lane & 15, lh = lane >> 4;
  const int wr = (wid >> 1) * 64;   // rows 0-63 / 64-127
  const int wc = (wid & 1) * 128;   // cols 0-127 / 128-255
  const int rowBase = blockIdx.x * 128;

  auto stage = [&](int t) {
    char* dA = lds + (t % 3) * 24576;
    char* dB = dA + 8192;
    #pragma unroll
    for (int i = 0; i < 2; ++i) {                   // A: 128 rows x 32 K = 8KB
      int off = (i * 256 + tid) * 16;
      int r = off >> 6, cb = off & 63;
      int csw = cb ^ ((r & 3) << 4);
      gload_lds16((const char*)(A + (size_t)(rowBase + r) * 1024 + t * 32) + csw, dA + off);
    }
    #pragma unroll
    for (int i = 0; i < 4; ++i) {                   // B: 256 rows x 32 K = 16KB
      int off = (i * 256 + tid) * 16;
      int r = off >> 6, cb = off & 63;
      int csw = cb ^ ((r & 3) << 4);
      gload_lds16((const char*)(Bw + (size_t)r * 1024 + t * 32) + csw, dB + off);
    }
  };

  f32x4 acc[4][8];
  #pragma unroll
  for (int m = 0; m < 4; ++m)
    #pragma unroll
    for (int n = 0; n < 8; ++n) acc[m][n] = (f32x4){0.f,0.f,0.f,0.f};

  stage(0);
  stage(1);
  asm volatile("s_waitcnt vmcnt(6)" ::: "memory");   // younger-than-stage(0) = stage(1)=6
  __builtin_amdgcn_sched_barrier(0);

  for (int t = 0; t < 32; ++t) {
    __builtin_amdgcn_s_barrier();
    __builtin_amdgcn_sched_barrier(0);

    if (t + 2 < 32) stage(t + 2);

    const char* bufA = lds + (t % 3) * 24576;
    const char* bufB = bufA + 8192;
    bf16x8 af[4], bfr[8];
    #pragma unroll
    for (int m = 0; m < 4; ++m) {
      int rA = wr + m * 16 + l15;
      af[m] = *(const bf16x8*)(bufA + rA * 64 + ((lh * 16) ^ ((rA & 3) << 4)));
    }
    #pragma unroll
    for (int n = 0; n < 8; ++n) {
      int rB = wc + n * 16 + l15;
      bfr[n] = *(const bf16x8*)(bufB + rB * 64 + ((lh * 16) ^ ((rB & 3) << 4)));
    }
    #pragma unroll
    for (int m = 0; m < 4; ++m)
      #pragma unroll
      for (int n = 0; n < 8; ++n)
        acc[m][n] = __builtin_amdgcn_mfma_f32_16x16x32_bf16(bfr[n], af[m], acc[m][n], 0, 0, 0);

    asm volatile("s_waitcnt vmcnt(6)" ::: "memory"); // younger-than-stage(t+1) = stage(t+2)=6
    __builtin_amdgcn_sched_barrier(0);
  }

  // epilogue: x1 += acc + b2 (f32 RMW), rows rowBase+wr+m*16+l15, cols wc+n*16+lh*4
  #pragma unroll
  for (int m = 0; m < 4; ++m) {
    size_t rowAddr = (size_t)(rowBase + wr + m * 16 + l15) * 256;
    #pragma unroll
    for (int n = 0; n < 8; ++n) {
      const int colb = wc + n * 16 + lh * 4;
      const f32x4 b4 = *(const f32x4*)(bias + colb);
      f32x4* p = (f32x4*)(Cf + rowAddr + colb);
      f32x4 cc = *p;
      #pragma unroll
      for (int j = 0; j < 4; ++j) cc[j] += acc[m][n][j] + b4[j];
      *p = cc;
    }
  }
}

// ---------------- attention: 1 wave per (window, head) ----------------
__global__ __launch_bounds__(256) void k_attn(
    const bf16* __restrict__ qkv, const float* __restrict__ btab,
    bf16* __restrict__ outp)
{
  __shared__ __align__(16) char smem[71680];
  float* sb = (float*)smem;                        // 64*64 f32 bias for this head
  const int tid = threadIdx.x, wid = tid >> 6, lane = tid & 63;
  const int l15 = lane & 15, lh = lane >> 4;
  const int h = blockIdx.x >> 8;
  const int win = ((blockIdx.x & 255) << 2) + wid;
  const int tb = win << 6;
  char* plw = smem + 16384 + wid * 9216;           // P: 64 rows x 144B
  char* vtw = smem + 16384 + 36864 + wid * 4608;   // Vt: 32 rows x 144B

  for (int i = tid; i < 4096; i += 256) sb[i] = btab[(h << 12) + i];
  __syncthreads();

  bf16x8 qf[4], kf[4];
  #pragma unroll
  for (int m = 0; m < 4; ++m) {
    size_t base = (size_t)(tb + m * 16 + l15) * 768 + h * 32 + lh * 8;
    qf[m] = *(const bf16x8*)(qkv + base);
    kf[m] = *(const bf16x8*)(qkv + base + 256);
  }
  f32x4 s[4][4];
  #pragma unroll
  for (int i = 0; i < 4; ++i)
    #pragma unroll
    for (int j = 0; j < 4; ++j) {
      s[i][j] = (f32x4){0.f,0.f,0.f,0.f};
      s[i][j] = __builtin_amdgcn_mfma_f32_16x16x32_bf16(qf[i], kf[j], s[i][j], 0, 0, 0);
    }

  #pragma unroll
  for (int it = 0; it < 32; ++it) {
    int idx = it * 64 + lane;
    int m = idx >> 5, d = idx & 31;
    bf16 vv = qkv[(size_t)(tb + m) * 768 + 512 + h * 32 + d];
    *(bf16*)(vtw + d * 144 + m * 2) = vv;
  }

  int ww = win & 63, wi = ww >> 3, wj = ww & 7;
  int labm[4];
  #pragma unroll
  for (int jf = 0; jf < 4; ++jf) {
    int m = jf * 16 + l15;
    int yy = wi * 8 + (m >> 3), xx = wj * 8 + (m & 7);
    labm[jf] = (yy < 56 ? 0 : (yy < 60 ? 1 : 2)) * 3 + (xx < 56 ? 0 : (xx < 60 ? 1 : 2));
  }
  float rsum[4][4];
  const float scale = 0.17677669529663687f;  // 1/sqrt(32)
  #pragma unroll
  for (int i = 0; i < 4; ++i) {
    #pragma unroll
    for (int j = 0; j < 4; ++j) {
      int n = i * 16 + lh * 4 + j;
      int yy = wi * 8 + (n >> 3), xx = wj * 8 + (n & 7);
      int labn = (yy < 56 ? 0 : (yy < 60 ? 1 : 2)) * 3 + (xx < 56 ? 0 : (xx < 60 ? 1 : 2));
      float vals[4]; float mx = -1e30f;
      #pragma unroll
      for (int jf = 0; jf < 4; ++jf) {
        int m = jf * 16 + l15;
        float v = s[i][jf][j] * scale + sb[(n << 6) + m];
        if (labn != labm[jf]) v -= 100.0f;
        vals[jf] = v; mx = fmaxf(mx, v);
      }
      #pragma unroll
      for (int o = 1; o < 16; o <<= 1) mx = fmaxf(mx, __shfl_xor(mx, o));
      float sum = 0.0f;
      #pragma unroll
      for (int jf = 0; jf < 4; ++jf) {
        float e = __expf(vals[jf] - mx);
        sum += e;
        *(bf16*)(plw + n * 144 + (jf * 16 + l15) * 2) = __float2bfloat16(e);
      }
      #pragma unroll
      for (int o = 1; o < 16; o <<= 1) sum += __shfl_xor(sum, o);
      rsum[i][j] = sum;
    }
  }
  __syncthreads();

  f32x4 o[4][2];
  #pragma unroll
  for (int i = 0; i < 4; ++i) { o[i][0] = (f32x4){0.f,0.f,0.f,0.f}; o[i][1] = (f32x4){0.f,0.f,0.f,0.f}; }
  #pragma unroll
  for (int kk = 0; kk < 2; ++kk) {
    bf16x8 pf[4], vf[2];
    #pragma unroll
    for (int i = 0; i < 4; ++i)
      pf[i] = *(const bf16x8*)(plw + (i * 16 + l15) * 144 + kk * 64 + lh * 16);
    #pragma unroll
    for (int df = 0; df < 2; ++df)
      vf[df] = *(const bf16x8*)(vtw + (df * 16 + l15) * 144 + kk * 64 + lh * 16);
    #pragma unroll
    for (int i = 0; i < 4; ++i)
      #pragma unroll
      for (int df = 0; df < 2; ++df)
        o[i][df] = __builtin_amdgcn_mfma_f32_16x16x32_bf16(pf[i], vf[df], o[i][df], 0, 0, 0);
  }
  #pragma unroll
  for (int i = 0; i < 4; ++i)
    #pragma unroll
    for (int df = 0; df < 2; ++df)
      #pragma unroll
      for (int j = 0; j < 4; ++j) {
        int n = i * 16 + lh * 4 + j;
        int d = df * 16 + l15;
        float v = o[i][df][j] / rsum[i][j];
        outp[(size_t)(tb + n) * 256 + h * 32 + d] = __float2bfloat16(v);
      }
}

// ---------------- launch ----------------
extern "C" void kernel_launch(void* const* d_in, const int* in_sizes, int n_in,
                              void* d_out, int out_size, void* d_ws, size_t ws_size,
                              hipStream_t stream) {
  (void)in_sizes; (void)n_in; (void)out_size; (void)ws_size;
  const float* x      = (const float*)d_in[0];
  const float* ln1_s  = (const float*)d_in[1];
  const float* ln1_b  = (const float*)d_in[2];
  const float* qkv_w  = (const float*)d_in[3];
  const float* qkv_b  = (const float*)d_in[4];
  const float* proj_w = (const float*)d_in[5];
  const float* proj_b = (const float*)d_in[6];
  const float* rel_b  = (const float*)d_in[7];
  const float* ln2_s  = (const float*)d_in[8];
  const float* ln2_b  = (const float*)d_in[9];
  const float* w1     = (const float*)d_in[10];
  const float* b1     = (const float*)d_in[11];
  const float* w2     = (const float*)d_in[12];
  const float* b2     = (const float*)d_in[13];

  char* ws = (char*)d_ws;
  bf16*  wqkv  = (bf16*)(ws + 0);               // 196608 el
  bf16*  wproj = wqkv + 196608;                 // 65536 el
  bf16*  wm1   = wqkv + 262144;                 // 262144 el
  bf16*  wm2   = wqkv + 524288;                 // 262144 el
  float* btab  = (float*)(ws + 1572864);        // 32768 f32
  bf16*  hbuf  = (bf16*)(ws + 2097152);         // 65536x256 (34MB..)
  bf16*  qkvb  = (bf16*)(ws + 35651584);        // 65536x768 (34MB..134MB)
  bf16*  attnb = (bf16*)(ws + 136314880);       // 65536x256 (130MB..163MB)
  bf16*  ln2buf = hbuf;                         // reuse (h dead after QKV gemm)
  bf16*  actb  = qkvb;                          // 65536x1024 (qkv+attn dead after proj)
  float* x1    = (float*)d_out;                 // residual lives in d_out

  k_conv_weights<<<3072, 256, 0, stream>>>(qkv_w, proj_w, w1, w2, wqkv);
  k_build_btab<<<128, 256, 0, stream>>>(rel_b, btab);
  k_ln1_window<<<16384, 256, 0, stream>>>(x, ln1_s, ln1_b, hbuf);
  k_pipe_ar<0><<<1024, 256, 0, stream>>>(hbuf, wqkv, qkv_b, nullptr, qkvb, nullptr, 768);
  k_attn<<<2048, 256, 0, stream>>>(qkvb, btab, attnb);
  k_pipe_ar<2><<<1024, 256, 0, stream>>>(attnb, wproj, proj_b, x1, nullptr, x, 256);
  k_ln2<<<16384, 256, 0, stream>>>(x1, ln2_s, ln2_b, ln2buf);
  k_pipe_ar<1><<<1024, 256, 0, stream>>>(ln2buf, wm1, b1, nullptr, actb, nullptr, 1024);
  k_pipe_bt<<<512, 256, 0, stream>>>(actb, wm2, b2, x1);
}

// Round 8
// 322.362 us; speedup vs baseline: 2.1630x; 1.2238x over previous
//
#include <hip/hip_runtime.h>
#include <hip/hip_bf16.h>
#include <math.h>

#define AS1 __attribute__((address_space(1)))
#define AS3 __attribute__((address_space(3)))

typedef __bf16  bf16x8 __attribute__((ext_vector_type(8)));
typedef float   f32x4  __attribute__((ext_vector_type(4)));
typedef __hip_bfloat16 bf16;

__device__ __forceinline__ void gload_lds16(const void* g, void* l) {
  __builtin_amdgcn_global_load_lds((const AS1 void*)g, (AS3 void*)l, 16, 0, 0);
}

// ---------------- weight conversion f32 -> bf16 ----------------
__global__ __launch_bounds__(256) void k_conv_weights(
    const float* __restrict__ qkvw, const float* __restrict__ projw,
    const float* __restrict__ w1, const float* __restrict__ w2,
    bf16* __restrict__ dst)
{
  int i = blockIdx.x * 256 + threadIdx.x;   // grid covers exactly 786432
  float v;
  if (i < 196608)       v = qkvw[i];
  else if (i < 262144)  v = projw[i - 196608];
  else if (i < 524288)  v = w1[i - 262144];
  else                  v = w2[i - 524288];
  dst[i] = __float2bfloat16(v);
}

// ---------------- rel-pos bias table: btab[h][n][m] ----------------
__global__ __launch_bounds__(256) void k_build_btab(
    const float* __restrict__ rel_bias, float* __restrict__ btab)
{
  int i = blockIdx.x * 256 + threadIdx.x;   // 32768
  int h = i >> 12, r = i & 4095, n = r >> 6, m = r & 63;
  int idx = ((n >> 3) - (m >> 3) + 7) * 15 + ((n & 7) - (m & 7) + 7);
  btab[i] = rel_bias[idx * 8 + h];
}

// ---------------- LN1 + roll(-4,-4) + window partition, f32 -> bf16 ----------------
__global__ __launch_bounds__(256) void k_ln1_window(
    const float* __restrict__ x, const float* __restrict__ sc,
    const float* __restrict__ bi, bf16* __restrict__ hout)
{
  int t = blockIdx.x * 4 + (threadIdx.x >> 6);
  int lane = threadIdx.x & 63;
  int win = t >> 6, nn = t & 63;
  int b = win >> 6, ww = win & 63;
  int ry = ((ww >> 3) << 3) + (nn >> 3);
  int rx = ((ww & 7) << 3) + (nn & 7);
  int sy = (ry + 4) & 63, sx = (rx + 4) & 63;
  const float* src = x + ((size_t)(((b << 6) + sy) << 6) + sx) * 256;
  f32x4 v = *(const f32x4*)(src + lane * 4);
  float s = v[0] + v[1] + v[2] + v[3];
  #pragma unroll
  for (int o = 1; o < 64; o <<= 1) s += __shfl_xor(s, o);
  float mu = s * (1.0f / 256.0f);
  float d0 = v[0]-mu, d1 = v[1]-mu, d2 = v[2]-mu, d3 = v[3]-mu;
  float q = d0*d0 + d1*d1 + d2*d2 + d3*d3;
  #pragma unroll
  for (int o = 1; o < 64; o <<= 1) q += __shfl_xor(q, o);
  float rstd = rsqrtf(q * (1.0f / 256.0f) + 1e-5f);
  int c = lane * 4;
  union { bf16 h[4]; uint2 u; } pk;
  pk.h[0] = __float2bfloat16(d0 * rstd * sc[c+0] + bi[c+0]);
  pk.h[1] = __float2bfloat16(d1 * rstd * sc[c+1] + bi[c+1]);
  pk.h[2] = __float2bfloat16(d2 * rstd * sc[c+2] + bi[c+2]);
  pk.h[3] = __float2bfloat16(d3 * rstd * sc[c+3] + bi[c+3]);
  *(uint2*)(hout + (size_t)t * 256 + c) = pk.u;
}

// ---------------- LN2 (pixel-major), f32 -> bf16 ----------------
__global__ __launch_bounds__(256) void k_ln2(
    const float* __restrict__ x1, const float* __restrict__ sc,
    const float* __restrict__ bi, bf16* __restrict__ out)
{
  int t = blockIdx.x * 4 + (threadIdx.x >> 6);
  int lane = threadIdx.x & 63;
  const float* src = x1 + (size_t)t * 256;
  f32x4 v = *(const f32x4*)(src + lane * 4);
  float s = v[0] + v[1] + v[2] + v[3];
  #pragma unroll
  for (int o = 1; o < 64; o <<= 1) s += __shfl_xor(s, o);
  float mu = s * (1.0f / 256.0f);
  float d0 = v[0]-mu, d1 = v[1]-mu, d2 = v[2]-mu, d3 = v[3]-mu;
  float q = d0*d0 + d1*d1 + d2*d2 + d3*d3;
  #pragma unroll
  for (int o = 1; o < 64; o <<= 1) q += __shfl_xor(q, o);
  float rstd = rsqrtf(q * (1.0f / 256.0f) + 1e-5f);
  int c = lane * 4;
  union { bf16 h[4]; uint2 u; } pk;
  pk.h[0] = __float2bfloat16(d0 * rstd * sc[c+0] + bi[c+0]);
  pk.h[1] = __float2bfloat16(d1 * rstd * sc[c+1] + bi[c+1]);
  pk.h[2] = __float2bfloat16(d2 * rstd * sc[c+2] + bi[c+2]);
  pk.h[3] = __float2bfloat16(d3 * rstd * sc[c+3] + bi[c+3]);
  *(uint2*)(out + (size_t)t * 256 + c) = pk.u;
}

// ============ A-resident N-streaming GEMM (K=256), counted-vmcnt pipeline v2 ============
// Block: 128 rows (4 waves x 32 rows); per wave full-K A in regs (af[2][8]).
// N streamed in 32-col chunks; B-chunk 16KB staged into 3-buffer LDS ring.
// Per chunk per wave: 32 MFMA. Bias/resid loads software-pipelined one chunk
// ahead so their consumption never drains the stage queue. Counted vmcnt keeps
// stage(c+1),(c+2) in flight across barriers; tail uses conservative waits.
// EPI 0: bf16 store | EPI 1: GELU -> bf16 | EPI 2: proj remap + resid, f32
template<int EPI>
__global__ __launch_bounds__(256, 2) void k_pipe_ar(
    const bf16* __restrict__ A, const bf16* __restrict__ Bw,
    const float* __restrict__ bias,
    float* __restrict__ Cf, bf16* __restrict__ Cb,
    const float* __restrict__ resid, int N)
{
  __shared__ __align__(16) char lds[49152];   // 3 x 16KB ring

  const int tid = threadIdx.x;
  const int wid = tid >> 6;
  const int lane = tid & 63;
  const int l15 = lane & 15, lh = lane >> 4;
  const int rowBase = blockIdx.x * 128 + wid * 32;
  const int NC = N >> 5;

  auto stage = [&](int c) {   // 4 vmem ops per thread
    char* dst = lds + (c % 3) * 16384;
    const char* srcB = (const char*)Bw + (size_t)c * 32 * 512;
    #pragma unroll
    for (int i = 0; i < 4; ++i) {
      int off = (i * 256 + tid) * 16;
      int r = off >> 9, cb = off & 511;
      int csw = cb ^ ((r & 7) << 4);
      gload_lds16(srcB + (size_t)r * 512 + csw, dst + off);
    }
  };

  // ---- one-time A fragment load (32 rows x K=256 per wave) : 16 ops ----
  bf16x8 af[2][8];
  {
    const bf16* a0 = A + (size_t)(rowBase + l15) * 256 + lh * 8;
    #pragma unroll
    for (int kk = 0; kk < 8; ++kk) {
      af[0][kk] = *(const bf16x8*)(a0 + kk * 32);
      af[1][kk] = *(const bf16x8*)(a0 + 4096 + kk * 32);   // +16 rows
    }
  }

  // ---- store row addresses ----
  size_t ra0, ra1;
  #pragma unroll
  for (int m = 0; m < 2; ++m) {
    int row = rowBase + m * 16 + l15;
    size_t ra;
    if (EPI == 2) {
      int win = row >> 6, nn = row & 63;
      int b = win >> 6, ww = win & 63;
      int ry = ((ww >> 3) << 3) + (nn >> 3);
      int rx = ((ww & 7) << 3) + (nn & 7);
      int fy = (ry + 4) & 63, fx = (rx + 4) & 63;
      ra = ((size_t)(((b << 6) + fy) << 6) + fx) * 256;
    } else {
      ra = (size_t)row * N;
    }
    if (m == 0) ra0 = ra; else ra1 = ra;
  }

  // ---- prologue: bias/resid for chunk 0, then stage(0), stage(1) ----
  const int cl = lh * 4;                  // within-chunk col offset
  f32x4 bc0 = *(const f32x4*)(bias + cl);
  f32x4 bc1 = *(const f32x4*)(bias + cl + 16);
  f32x4 rc00, rc10, rc01, rc11;
  if (EPI == 2) {
    rc00 = *(const f32x4*)(resid + ra0 + cl);
    rc10 = *(const f32x4*)(resid + ra1 + cl);
    rc01 = *(const f32x4*)(resid + ra0 + cl + 16);
    rc11 = *(const f32x4*)(resid + ra1 + cl + 16);
  }
  stage(0);
  stage(1);
  asm volatile("s_waitcnt vmcnt(4)" ::: "memory");   // stage(0) done; stage(1) flying
  __builtin_amdgcn_sched_barrier(0);

  for (int c = 0; c < NC; ++c) {
    __builtin_amdgcn_s_barrier();                    // stage(c) visible to all
    __builtin_amdgcn_sched_barrier(0);

    // prefetch NEXT chunk's bias/resid (consumed next iter -> no drain hazard)
    f32x4 bn0, bn1, rn00, rn10, rn01, rn11;
    if (c + 1 < NC) {
      const int ncl = (c + 1) * 32 + cl;
      bn0 = *(const f32x4*)(bias + ncl);
      bn1 = *(const f32x4*)(bias + ncl + 16);
      if (EPI == 2) {
        rn00 = *(const f32x4*)(resid + ra0 + ncl);
        rn10 = *(const f32x4*)(resid + ra1 + ncl);
        rn01 = *(const f32x4*)(resid + ra0 + ncl + 16);
        rn11 = *(const f32x4*)(resid + ra1 + ncl + 16);
      }
    }
    if (c + 2 < NC) stage(c + 2);

    // ---- compute: 16 ds_reads, 32 MFMA ----
    const char* buf = lds + (c % 3) * 16384;
    const int xr = (l15 & 7) << 4;
    f32x4 a00 = (f32x4){0.f,0.f,0.f,0.f};
    f32x4 a10 = (f32x4){0.f,0.f,0.f,0.f};
    f32x4 a01 = (f32x4){0.f,0.f,0.f,0.f};
    f32x4 a11 = (f32x4){0.f,0.f,0.f,0.f};
    #pragma unroll
    for (int kk = 0; kk < 8; ++kk) {
      const int ko = (kk * 64 + lh * 16) ^ xr;
      bf16x8 b0 = *(const bf16x8*)(buf + (size_t)l15 * 512 + ko);
      bf16x8 b1 = *(const bf16x8*)(buf + (size_t)(16 + l15) * 512 + ko);
      a00 = __builtin_amdgcn_mfma_f32_16x16x32_bf16(b0, af[0][kk], a00, 0, 0, 0);
      a10 = __builtin_amdgcn_mfma_f32_16x16x32_bf16(b0, af[1][kk], a10, 0, 0, 0);
      a01 = __builtin_amdgcn_mfma_f32_16x16x32_bf16(b1, af[0][kk], a01, 0, 0, 0);
      a11 = __builtin_amdgcn_mfma_f32_16x16x32_bf16(b1, af[1][kk], a11, 0, 0, 0);
    }

    // ---- epilogue: 4 stores (uses PRE-LOADED bias/resid) ----
    const int colb0 = c * 32 + cl;
    const int colb1 = colb0 + 16;
    if (EPI == 0) {
      union { bf16 h[4]; uint2 u; } p;
      #pragma unroll
      for (int j = 0; j < 4; ++j) p.h[j] = __float2bfloat16(a00[j] + bc0[j]);
      *(uint2*)(Cb + ra0 + colb0) = p.u;
      #pragma unroll
      for (int j = 0; j < 4; ++j) p.h[j] = __float2bfloat16(a10[j] + bc0[j]);
      *(uint2*)(Cb + ra1 + colb0) = p.u;
      #pragma unroll
      for (int j = 0; j < 4; ++j) p.h[j] = __float2bfloat16(a01[j] + bc1[j]);
      *(uint2*)(Cb + ra0 + colb1) = p.u;
      #pragma unroll
      for (int j = 0; j < 4; ++j) p.h[j] = __float2bfloat16(a11[j] + bc1[j]);
      *(uint2*)(Cb + ra1 + colb1) = p.u;
    } else if (EPI == 1) {
      auto gelu = [](float v) {
        float w = fmaf(v * v, 0.1029434f, 2.3022083f);   // ln2-folded tanh-GELU
        float e = __builtin_amdgcn_exp2f(-v * w);
        return v * __builtin_amdgcn_rcpf(1.0f + e);
      };
      union { bf16 h[4]; uint2 u; } p;
      #pragma unroll
      for (int j = 0; j < 4; ++j) p.h[j] = __float2bfloat16(gelu(a00[j] + bc0[j]));
      *(uint2*)(Cb + ra0 + colb0) = p.u;
      #pragma unroll
      for (int j = 0; j < 4; ++j) p.h[j] = __float2bfloat16(gelu(a10[j] + bc0[j]));
      *(uint2*)(Cb + ra1 + colb0) = p.u;
      #pragma unroll
      for (int j = 0; j < 4; ++j) p.h[j] = __float2bfloat16(gelu(a01[j] + bc1[j]));
      *(uint2*)(Cb + ra0 + colb1) = p.u;
      #pragma unroll
      for (int j = 0; j < 4; ++j) p.h[j] = __float2bfloat16(gelu(a11[j] + bc1[j]));
      *(uint2*)(Cb + ra1 + colb1) = p.u;
    } else {
      f32x4 o;
      #pragma unroll
      for (int j = 0; j < 4; ++j) o[j] = a00[j] + bc0[j] + rc00[j];
      *(f32x4*)(Cf + ra0 + colb0) = o;
      #pragma unroll
      for (int j = 0; j < 4; ++j) o[j] = a10[j] + bc0[j] + rc10[j];
      *(f32x4*)(Cf + ra1 + colb0) = o;
      #pragma unroll
      for (int j = 0; j < 4; ++j) o[j] = a01[j] + bc1[j] + rc01[j];
      *(f32x4*)(Cf + ra0 + colb1) = o;
      #pragma unroll
      for (int j = 0; j < 4; ++j) o[j] = a11[j] + bc1[j] + rc11[j];
      *(f32x4*)(Cf + ra1 + colb1) = o;
    }

    // rotate prefetched operands
    if (c + 1 < NC) {
      bc0 = bn0; bc1 = bn1;
      if (EPI == 2) { rc00 = rn00; rc10 = rn10; rc01 = rn01; rc11 = rn11; }
    }

    // ---- guarantee stage(c+1) retired before next barrier; keep stage(c+2),
    //      this chunk's loads/stores, and prev stores in flight.
    // younger-than-stage(c+1) steady = stores(c-1)4 + bias2 [+resid4] + stage4 + stores4
    if (c + 1 < NC) {
      if (EPI == 2) {
        if (c > 0 && c + 2 < NC) { asm volatile("s_waitcnt vmcnt(18)" ::: "memory"); }
        else                     { asm volatile("s_waitcnt vmcnt(10)" ::: "memory"); }
      } else {
        if (c > 0 && c + 2 < NC) { asm volatile("s_waitcnt vmcnt(14)" ::: "memory"); }
        else                     { asm volatile("s_waitcnt vmcnt(6)"  ::: "memory"); }
      }
      __builtin_amdgcn_sched_barrier(0);
    }
  }
}

// ============ MLP2 pipelined GEMM: x1 += act @ W2^T + b2 (K=1024, N=256) ============
// BM=128 rows/block, full N=256 in acc[4][8]; BKK=32; 3-buf ring; counted vmcnt;
// tail iterations drain (race fix). A streamed from HBM once.
__global__ __launch_bounds__(256, 2) void k_pipe_bt(
    const bf16* __restrict__ A, const bf16* __restrict__ Bw,
    const float* __restrict__ bias, float* __restrict__ Cf)
{
  __shared__ __align__(16) char lds[73728];   // 3 x (8KB A + 16KB B)

  const int tid = threadIdx.x;
  const int wid = tid >> 6;
  const int lane = tid & 63;
  const int l15 = lane & 15, lh = lane >> 4;
  const int wr = (wid >> 1) * 64;   // rows 0-63 / 64-127
  const int wc = (wid & 1) * 128;   // cols 0-127 / 128-255
  const int rowBase = blockIdx.x * 128;

  auto stage = [&](int t) {   // 6 vmem ops per thread
    char* dA = lds + (t % 3) * 24576;
    char* dB = dA + 8192;
    #pragma unroll
    for (int i = 0; i < 2; ++i) {                   // A: 128 rows x 32 K = 8KB
      int off = (i * 256 + tid) * 16;
      int r = off >> 6, cb = off & 63;
      int csw = cb ^ ((r & 3) << 4);
      gload_lds16((const char*)(A + (size_t)(rowBase + r) * 1024 + t * 32) + csw, dA + off);
    }
    #pragma unroll
    for (int i = 0; i < 4; ++i) {                   // B: 256 rows x 32 K = 16KB
      int off = (i * 256 + tid) * 16;
      int r = off >> 6, cb = off & 63;
      int csw = cb ^ ((r & 3) << 4);
      gload_lds16((const char*)(Bw + (size_t)r * 1024 + t * 32) + csw, dB + off);
    }
  };

  f32x4 acc[4][8];
  #pragma unroll
  for (int m = 0; m < 4; ++m)
    #pragma unroll
    for (int n = 0; n < 8; ++n) acc[m][n] = (f32x4){0.f,0.f,0.f,0.f};

  stage(0);
  stage(1);
  asm volatile("s_waitcnt vmcnt(6)" ::: "memory");   // stage(0) done; stage(1) flying
  __builtin_amdgcn_sched_barrier(0);

  for (int t = 0; t < 32; ++t) {
    __builtin_amdgcn_s_barrier();
    __builtin_amdgcn_sched_barrier(0);

    if (t + 2 < 32) stage(t + 2);

    const char* bufA = lds + (t % 3) * 24576;
    const char* bufB = bufA + 8192;
    bf16x8 af[4], bfr[8];
    #pragma unroll
    for (int m = 0; m < 4; ++m) {
      int rA = wr + m * 16 + l15;
      af[m] = *(const bf16x8*)(bufA + rA * 64 + ((lh * 16) ^ ((rA & 3) << 4)));
    }
    #pragma unroll
    for (int n = 0; n < 8; ++n) {
      int rB = wc + n * 16 + l15;
      bfr[n] = *(const bf16x8*)(bufB + rB * 64 + ((lh * 16) ^ ((rB & 3) << 4)));
    }
    #pragma unroll
    for (int m = 0; m < 4; ++m)
      #pragma unroll
      for (int n = 0; n < 8; ++n)
        acc[m][n] = __builtin_amdgcn_mfma_f32_16x16x32_bf16(bfr[n], af[m], acc[m][n], 0, 0, 0);

    if (t + 2 < 32) { asm volatile("s_waitcnt vmcnt(6)" ::: "memory"); }   // stage(t+1) done
    else if (t < 31) { asm volatile("s_waitcnt vmcnt(0)" ::: "memory"); }  // tail drain (race fix)
    __builtin_amdgcn_sched_barrier(0);
  }

  // epilogue: x1 += acc + b2 (f32 RMW)
  #pragma unroll
  for (int m = 0; m < 4; ++m) {
    size_t rowAddr = (size_t)(rowBase + wr + m * 16 + l15) * 256;
    #pragma unroll
    for (int n = 0; n < 8; ++n) {
      const int colb = wc + n * 16 + lh * 4;
      const f32x4 b4 = *(const f32x4*)(bias + colb);
      f32x4* p = (f32x4*)(Cf + rowAddr + colb);
      f32x4 cc = *p;
      #pragma unroll
      for (int j = 0; j < 4; ++j) cc[j] += acc[m][n][j] + b4[j];
      *p = cc;
    }
  }
}

// ---------------- attention: 1 wave per (window, head) ----------------
__global__ __launch_bounds__(256) void k_attn(
    const bf16* __restrict__ qkv, const float* __restrict__ btab,
    bf16* __restrict__ outp)
{
  __shared__ __align__(16) char smem[71680];
  float* sb = (float*)smem;                        // 64*64 f32 bias for this head
  const int tid = threadIdx.x, wid = tid >> 6, lane = tid & 63;
  const int l15 = lane & 15, lh = lane >> 4;
  const int h = blockIdx.x >> 8;
  const int win = ((blockIdx.x & 255) << 2) + wid;
  const int tb = win << 6;
  char* plw = smem + 16384 + wid * 9216;           // P: 64 rows x 144B
  char* vtw = smem + 16384 + 36864 + wid * 4608;   // Vt: 32 rows x 144B

  for (int i = tid; i < 4096; i += 256) sb[i] = btab[(h << 12) + i];
  __syncthreads();

  bf16x8 qf[4], kf[4];
  #pragma unroll
  for (int m = 0; m < 4; ++m) {
    size_t base = (size_t)(tb + m * 16 + l15) * 768 + h * 32 + lh * 8;
    qf[m] = *(const bf16x8*)(qkv + base);
    kf[m] = *(const bf16x8*)(qkv + base + 256);
  }
  f32x4 s[4][4];
  #pragma unroll
  for (int i = 0; i < 4; ++i)
    #pragma unroll
    for (int j = 0; j < 4; ++j) {
      s[i][j] = (f32x4){0.f,0.f,0.f,0.f};
      s[i][j] = __builtin_amdgcn_mfma_f32_16x16x32_bf16(qf[i], kf[j], s[i][j], 0, 0, 0);
    }

  #pragma unroll
  for (int it = 0; it < 32; ++it) {
    int idx = it * 64 + lane;
    int m = idx >> 5, d = idx & 31;
    bf16 vv = qkv[(size_t)(tb + m) * 768 + 512 + h * 32 + d];
    *(bf16*)(vtw + d * 144 + m * 2) = vv;
  }

  int ww = win & 63, wi = ww >> 3, wj = ww & 7;
  int labm[4];
  #pragma unroll
  for (int jf = 0; jf < 4; ++jf) {
    int m = jf * 16 + l15;
    int yy = wi * 8 + (m >> 3), xx = wj * 8 + (m & 7);
    labm[jf] = (yy < 56 ? 0 : (yy < 60 ? 1 : 2)) * 3 + (xx < 56 ? 0 : (xx < 60 ? 1 : 2));
  }
  float rsum[4][4];
  const float scale = 0.17677669529663687f;  // 1/sqrt(32)
  #pragma unroll
  for (int i = 0; i < 4; ++i) {
    #pragma unroll
    for (int j = 0; j < 4; ++j) {
      int n = i * 16 + lh * 4 + j;
      int yy = wi * 8 + (n >> 3), xx = wj * 8 + (n & 7);
      int labn = (yy < 56 ? 0 : (yy < 60 ? 1 : 2)) * 3 + (xx < 56 ? 0 : (xx < 60 ? 1 : 2));
      float vals[4]; float mx = -1e30f;
      #pragma unroll
      for (int jf = 0; jf < 4; ++jf) {
        int m = jf * 16 + l15;
        float v = s[i][jf][j] * scale + sb[(n << 6) + m];
        if (labn != labm[jf]) v -= 100.0f;
        vals[jf] = v; mx = fmaxf(mx, v);
      }
      #pragma unroll
      for (int o = 1; o < 16; o <<= 1) mx = fmaxf(mx, __shfl_xor(mx, o));
      float sum = 0.0f;
      #pragma unroll
      for (int jf = 0; jf < 4; ++jf) {
        float e = __expf(vals[jf] - mx);
        sum += e;
        *(bf16*)(plw + n * 144 + (jf * 16 + l15) * 2) = __float2bfloat16(e);
      }
      #pragma unroll
      for (int o = 1; o < 16; o <<= 1) sum += __shfl_xor(sum, o);
      rsum[i][j] = sum;
    }
  }
  __syncthreads();

  f32x4 o[4][2];
  #pragma unroll
  for (int i = 0; i < 4; ++i) { o[i][0] = (f32x4){0.f,0.f,0.f,0.f}; o[i][1] = (f32x4){0.f,0.f,0.f,0.f}; }
  #pragma unroll
  for (int kk = 0; kk < 2; ++kk) {
    bf16x8 pf[4], vf[2];
    #pragma unroll
    for (int i = 0; i < 4; ++i)
      pf[i] = *(const bf16x8*)(plw + (i * 16 + l15) * 144 + kk * 64 + lh * 16);
    #pragma unroll
    for (int df = 0; df < 2; ++df)
      vf[df] = *(const bf16x8*)(vtw + (df * 16 + l15) * 144 + kk * 64 + lh * 16);
    #pragma unroll
    for (int i = 0; i < 4; ++i)
      #pragma unroll
      for (int df = 0; df < 2; ++df)
        o[i][df] = __builtin_amdgcn_mfma_f32_16x16x32_bf16(pf[i], vf[df], o[i][df], 0, 0, 0);
  }
  #pragma unroll
  for (int i = 0; i < 4; ++i)
    #pragma unroll
    for (int df = 0; df < 2; ++df)
      #pragma unroll
      for (int j = 0; j < 4; ++j) {
        int n = i * 16 + lh * 4 + j;
        int d = df * 16 + l15;
        float v = o[i][df][j] / rsum[i][j];
        outp[(size_t)(tb + n) * 256 + h * 32 + d] = __float2bfloat16(v);
      }
}

// ---------------- launch ----------------
extern "C" void kernel_launch(void* const* d_in, const int* in_sizes, int n_in,
                              void* d_out, int out_size, void* d_ws, size_t ws_size,
                              hipStream_t stream) {
  (void)in_sizes; (void)n_in; (void)out_size; (void)ws_size;
  const float* x      = (const float*)d_in[0];
  const float* ln1_s  = (const float*)d_in[1];
  const float* ln1_b  = (const float*)d_in[2];
  const float* qkv_w  = (const float*)d_in[3];
  const float* qkv_b  = (const float*)d_in[4];
  const float* proj_w = (const float*)d_in[5];
  const float* proj_b = (const float*)d_in[6];
  const float* rel_b  = (const float*)d_in[7];
  const float* ln2_s  = (const float*)d_in[8];
  const float* ln2_b  = (const float*)d_in[9];
  const float* w1     = (const float*)d_in[10];
  const float* b1     = (const float*)d_in[11];
  const float* w2     = (const float*)d_in[12];
  const float* b2     = (const float*)d_in[13];

  char* ws = (char*)d_ws;
  bf16*  wqkv  = (bf16*)(ws + 0);               // 196608 el
  bf16*  wproj = wqkv + 196608;                 // 65536 el
  bf16*  wm1   = wqkv + 262144;                 // 262144 el
  bf16*  wm2   = wqkv + 524288;                 // 262144 el
  float* btab  = (float*)(ws + 1572864);        // 32768 f32
  bf16*  hbuf  = (bf16*)(ws + 2097152);         // 65536x256 (34MB..)
  bf16*  qkvb  = (bf16*)(ws + 35651584);        // 65536x768 (34MB..134MB)
  bf16*  attnb = (bf16*)(ws + 136314880);       // 65536x256 (130MB..163MB)
  bf16*  ln2buf = hbuf;                         // reuse (h dead after QKV gemm)
  bf16*  actb  = qkvb;                          // 65536x1024 (qkv+attn dead after proj)
  float* x1    = (float*)d_out;                 // residual lives in d_out

  k_conv_weights<<<3072, 256, 0, stream>>>(qkv_w, proj_w, w1, w2, wqkv);
  k_build_btab<<<128, 256, 0, stream>>>(rel_b, btab);
  k_ln1_window<<<16384, 256, 0, stream>>>(x, ln1_s, ln1_b, hbuf);
  k_pipe_ar<0><<<512, 256, 0, stream>>>(hbuf, wqkv, qkv_b, nullptr, qkvb, nullptr, 768);
  k_attn<<<2048, 256, 0, stream>>>(qkvb, btab, attnb);
  k_pipe_ar<2><<<512, 256, 0, stream>>>(attnb, wproj, proj_b, x1, nullptr, x, 256);
  k_ln2<<<16384, 256, 0, stream>>>(x1, ln2_s, ln2_b, ln2buf);
  k_pipe_ar<1><<<512, 256, 0, stream>>>(ln2buf, wm1, b1, nullptr, actb, nullptr, 1024);
  k_pipe_bt<<<512, 256, 0, stream>>>(actb, wm2, b2, x1);
}

// Round 9
// 309.440 us; speedup vs baseline: 2.2533x; 1.0418x over previous
//
#include <hip/hip_runtime.h>
#include <hip/hip_bf16.h>
#include <math.h>

#define AS1 __attribute__((address_space(1)))
#define AS3 __attribute__((address_space(3)))

typedef __bf16  bf16x8 __attribute__((ext_vector_type(8)));
typedef float   f32x4  __attribute__((ext_vector_type(4)));
typedef __hip_bfloat16 bf16;

__device__ __forceinline__ void gload_lds16(const void* g, void* l) {
  __builtin_amdgcn_global_load_lds((const AS1 void*)g, (AS3 void*)l, 16, 0, 0);
}

// ---------------- weight conversion f32 -> bf16 ----------------
__global__ __launch_bounds__(256) void k_conv_weights(
    const float* __restrict__ qkvw, const float* __restrict__ projw,
    const float* __restrict__ w1, const float* __restrict__ w2,
    bf16* __restrict__ dst)
{
  int i = blockIdx.x * 256 + threadIdx.x;   // grid covers exactly 786432
  float v;
  if (i < 196608)       v = qkvw[i];
  else if (i < 262144)  v = projw[i - 196608];
  else if (i < 524288)  v = w1[i - 262144];
  else                  v = w2[i - 524288];
  dst[i] = __float2bfloat16(v);
}

// ---------------- rel-pos bias table: btab[h][n][m] ----------------
__global__ __launch_bounds__(256) void k_build_btab(
    const float* __restrict__ rel_bias, float* __restrict__ btab)
{
  int i = blockIdx.x * 256 + threadIdx.x;   // 32768
  int h = i >> 12, r = i & 4095, n = r >> 6, m = r & 63;
  int idx = ((n >> 3) - (m >> 3) + 7) * 15 + ((n & 7) - (m & 7) + 7);
  btab[i] = rel_bias[idx * 8 + h];
}

// ---------------- LN1 + roll(-4,-4) + window partition, f32 -> bf16 ----------------
__global__ __launch_bounds__(256) void k_ln1_window(
    const float* __restrict__ x, const float* __restrict__ sc,
    const float* __restrict__ bi, bf16* __restrict__ hout)
{
  int t = blockIdx.x * 4 + (threadIdx.x >> 6);
  int lane = threadIdx.x & 63;
  int win = t >> 6, nn = t & 63;
  int b = win >> 6, ww = win & 63;
  int ry = ((ww >> 3) << 3) + (nn >> 3);
  int rx = ((ww & 7) << 3) + (nn & 7);
  int sy = (ry + 4) & 63, sx = (rx + 4) & 63;
  const float* src = x + ((size_t)(((b << 6) + sy) << 6) + sx) * 256;
  f32x4 v = *(const f32x4*)(src + lane * 4);
  float s = v[0] + v[1] + v[2] + v[3];
  #pragma unroll
  for (int o = 1; o < 64; o <<= 1) s += __shfl_xor(s, o);
  float mu = s * (1.0f / 256.0f);
  float d0 = v[0]-mu, d1 = v[1]-mu, d2 = v[2]-mu, d3 = v[3]-mu;
  float q = d0*d0 + d1*d1 + d2*d2 + d3*d3;
  #pragma unroll
  for (int o = 1; o < 64; o <<= 1) q += __shfl_xor(q, o);
  float rstd = rsqrtf(q * (1.0f / 256.0f) + 1e-5f);
  int c = lane * 4;
  union { bf16 h[4]; uint2 u; } pk;
  pk.h[0] = __float2bfloat16(d0 * rstd * sc[c+0] + bi[c+0]);
  pk.h[1] = __float2bfloat16(d1 * rstd * sc[c+1] + bi[c+1]);
  pk.h[2] = __float2bfloat16(d2 * rstd * sc[c+2] + bi[c+2]);
  pk.h[3] = __float2bfloat16(d3 * rstd * sc[c+3] + bi[c+3]);
  *(uint2*)(hout + (size_t)t * 256 + c) = pk.u;
}

// ============ A-resident N-streaming GEMM (K=256), depth-4 ring, exact vmcnt ============
// Block 128 rows (4 waves x 32); per-wave full-K A in regs (af[2][8], 64 VGPR).
// 32-col chunks, 4x16KB LDS ring, prefetch 3 ahead. Exact counted vmcnt (race-free):
// steady younger-than-stage(c+1) = 2 iterations of vmem ops. Bias/resid prefetched
// one chunk ahead. EPI0/1 stores go through a padded per-wave LDS bounce -> 16-row
// x 64B coalesced dwordx4 stores (kills write amplification).
// EPI 0: bf16 | EPI 1: GELU bf16 | EPI 2: proj remap + resid f32 + FUSED LN2 -> bf16
template<int EPI>
__global__ __launch_bounds__(256, 2) void k_pipe_ar(
    const bf16* __restrict__ A, const bf16* __restrict__ Bw,
    const float* __restrict__ bias,
    float* __restrict__ Cf, bf16* __restrict__ Cb,
    const float* __restrict__ resid,
    const float* __restrict__ ln2s, const float* __restrict__ ln2b,
    bf16* __restrict__ ln2out, int N)
{
  __shared__ __align__(16) char lds[65536 + 10240];   // 4x16KB ring + 4x2560B bounce

  const int tid = threadIdx.x;
  const int wid = tid >> 6;
  const int lane = tid & 63;
  const int l15 = lane & 15, lh = lane >> 4;
  const int rowBase = blockIdx.x * 128 + wid * 32;
  const int NC = N >> 5;
  char* scr = lds + 65536 + wid * 2560;   // 32 rows x 80B (64B data + 16B pad)

  auto stage = [&](int c) {   // 4 vmem ops/thread
    char* dst = lds + (c & 3) * 16384;
    const char* srcB = (const char*)Bw + (size_t)c * 32 * 512;
    #pragma unroll
    for (int i = 0; i < 4; ++i) {
      int off = (i * 256 + tid) * 16;
      int r = off >> 9, cb = off & 511;
      int csw = cb ^ ((r & 7) << 4);
      gload_lds16(srcB + (size_t)r * 512 + csw, dst + off);
    }
  };

  // ---- one-time A fragment load ----
  bf16x8 af[2][8];
  {
    const bf16* a0 = A + (size_t)(rowBase + l15) * 256 + lh * 8;
    #pragma unroll
    for (int kk = 0; kk < 8; ++kk) {
      af[0][kk] = *(const bf16x8*)(a0 + kk * 32);
      af[1][kk] = *(const bf16x8*)(a0 + 4096 + kk * 32);
    }
  }

  // ---- row addresses ----
  auto remap = [&](int row) -> size_t {
    int win = row >> 6, nn = row & 63;
    int b = win >> 6, ww = win & 63;
    int ry = ((ww >> 3) << 3) + (nn >> 3);
    int rx = ((ww & 7) << 3) + (nn & 7);
    int fy = (ry + 4) & 63, fx = (rx + 4) & 63;
    return ((size_t)(((b << 6) + fy) << 6) + fx) * 256;
  };
  size_t ra0 = 0, ra1 = 0;      // l15-based rows (EPI2 main loop + appendix)
  size_t rbA, rbB;              // bounce rows (lane>>2)
  if (EPI == 2) {
    ra0 = remap(rowBase + l15);
    ra1 = remap(rowBase + 16 + l15);
    rbA = remap(rowBase + (lane >> 2));       // ln2out rows (pixel-major)
    rbB = remap(rowBase + 16 + (lane >> 2));
  } else {
    rbA = (size_t)(rowBase + (lane >> 2)) * N;
    rbB = rbA + (size_t)16 * N;
  }

  // ---- prologue: bias/resid chunk0, then stage 0,1,2 ----
  const int cl = lh * 4;
  f32x4 bc0 = *(const f32x4*)(bias + cl);
  f32x4 bc1 = *(const f32x4*)(bias + cl + 16);
  f32x4 rc00, rc10, rc01, rc11;
  if (EPI == 2) {
    rc00 = *(const f32x4*)(resid + ra0 + cl);
    rc10 = *(const f32x4*)(resid + ra1 + cl);
    rc01 = *(const f32x4*)(resid + ra0 + cl + 16);
    rc11 = *(const f32x4*)(resid + ra1 + cl + 16);
  }
  stage(0); stage(1); stage(2);
  asm volatile("s_waitcnt vmcnt(8)" ::: "memory");   // stage(0) done
  __builtin_amdgcn_sched_barrier(0);

  float s0 = 0.f, q0 = 0.f, s1 = 0.f, q1 = 0.f;      // LN2 sums (EPI2)

  for (int c = 0; c < NC; ++c) {
    __builtin_amdgcn_s_barrier();
    __builtin_amdgcn_sched_barrier(0);

    f32x4 bn0, bn1, rn00, rn10, rn01, rn11;
    if (c + 1 < NC) {
      const int ncl = (c + 1) * 32 + cl;
      bn0 = *(const f32x4*)(bias + ncl);
      bn1 = *(const f32x4*)(bias + ncl + 16);
      if (EPI == 2) {
        rn00 = *(const f32x4*)(resid + ra0 + ncl);
        rn10 = *(const f32x4*)(resid + ra1 + ncl);
        rn01 = *(const f32x4*)(resid + ra0 + ncl + 16);
        rn11 = *(const f32x4*)(resid + ra1 + ncl + 16);
      }
    }
    if (c + 3 < NC) stage(c + 3);

    // ---- compute: 16 ds_reads, 32 MFMA ----
    const char* buf = lds + (c & 3) * 16384;
    const int xr = (l15 & 7) << 4;
    const int base0 = l15 * 512;
    f32x4 a00 = (f32x4){0.f,0.f,0.f,0.f};
    f32x4 a10 = (f32x4){0.f,0.f,0.f,0.f};
    f32x4 a01 = (f32x4){0.f,0.f,0.f,0.f};
    f32x4 a11 = (f32x4){0.f,0.f,0.f,0.f};
    #pragma unroll
    for (int kk = 0; kk < 8; ++kk) {
      const int ko = (kk * 64 + lh * 16) ^ xr;
      bf16x8 b0 = *(const bf16x8*)(buf + base0 + ko);
      bf16x8 b1 = *(const bf16x8*)(buf + base0 + 8192 + ko);
      a00 = __builtin_amdgcn_mfma_f32_16x16x32_bf16(b0, af[0][kk], a00, 0, 0, 0);
      a10 = __builtin_amdgcn_mfma_f32_16x16x32_bf16(b0, af[1][kk], a10, 0, 0, 0);
      a01 = __builtin_amdgcn_mfma_f32_16x16x32_bf16(b1, af[0][kk], a01, 0, 0, 0);
      a11 = __builtin_amdgcn_mfma_f32_16x16x32_bf16(b1, af[1][kk], a11, 0, 0, 0);
    }

    const int cbs = c * 32 + (lane & 3) * 8;    // bounce store col base
    if (EPI == 0 || EPI == 1) {
      auto cvt = [](float v) -> bf16 {
        if (EPI == 1) {
          float w = fmaf(v * v, 0.1029434f, 2.3022083f);   // ln2-folded tanh-GELU
          float e = __builtin_amdgcn_exp2f(-v * w);
          v = v * __builtin_amdgcn_rcpf(1.0f + e);
        }
        return __float2bfloat16(v);
      };
      union { bf16 h[4]; uint2 u; } p00, p01, p10, p11;
      #pragma unroll
      for (int j = 0; j < 4; ++j) {
        p00.h[j] = cvt(a00[j] + bc0[j]);
        p01.h[j] = cvt(a01[j] + bc1[j]);
        p10.h[j] = cvt(a10[j] + bc0[j]);
        p11.h[j] = cvt(a11[j] + bc1[j]);
      }
      // bounce: write (row-l15 layout), read back (row-quad layout), wide store
      *(uint2*)(scr + l15 * 80 + lh * 8)            = p00.u;
      *(uint2*)(scr + l15 * 80 + 32 + lh * 8)       = p01.u;
      *(uint2*)(scr + (16 + l15) * 80 + lh * 8)     = p10.u;
      *(uint2*)(scr + (16 + l15) * 80 + 32 + lh * 8)= p11.u;
      uint4 r0 = *(const uint4*)(scr + (lane >> 2) * 80 + (lane & 3) * 16);
      uint4 r1 = *(const uint4*)(scr + (16 + (lane >> 2)) * 80 + (lane & 3) * 16);
      *(uint4*)(Cb + rbA + cbs) = r0;
      *(uint4*)(Cb + rbB + cbs) = r1;
    } else {
      const int colb0 = c * 32 + cl, colb1 = colb0 + 16;
      f32x4 o00, o10, o01, o11;
      #pragma unroll
      for (int j = 0; j < 4; ++j) {
        o00[j] = a00[j] + bc0[j] + rc00[j];
        o10[j] = a10[j] + bc0[j] + rc10[j];
        o01[j] = a01[j] + bc1[j] + rc01[j];
        o11[j] = a11[j] + bc1[j] + rc11[j];
      }
      *(f32x4*)(Cf + ra0 + colb0) = o00;
      *(f32x4*)(Cf + ra1 + colb0) = o10;
      *(f32x4*)(Cf + ra0 + colb1) = o01;
      *(f32x4*)(Cf + ra1 + colb1) = o11;
      #pragma unroll
      for (int j = 0; j < 4; ++j) {
        s0 += o00[j] + o01[j];  q0 += o00[j]*o00[j] + o01[j]*o01[j];
        s1 += o10[j] + o11[j];  q1 += o10[j]*o10[j] + o11[j]*o11[j];
      }
    }

    if (c + 1 < NC) {
      bc0 = bn0; bc1 = bn1;
      if (EPI == 2) { rc00 = rn00; rc10 = rn10; rc01 = rn01; rc11 = rn11; }
    }

    // ---- exact counted wait: stage(c+1) retired before next barrier ----
    if (c + 1 < NC) {
      if (EPI == 2) {
        if (c == 0)            { asm volatile("s_waitcnt vmcnt(18)" ::: "memory"); }
        else if (c + 3 < NC)   { asm volatile("s_waitcnt vmcnt(28)" ::: "memory"); }
        else                   { asm volatile("s_waitcnt vmcnt(6)"  ::: "memory"); }
      } else {
        if (c == 0)            { asm volatile("s_waitcnt vmcnt(12)" ::: "memory"); }
        else if (c + 3 < NC)   { asm volatile("s_waitcnt vmcnt(16)" ::: "memory"); }
        else                   { asm volatile("s_waitcnt vmcnt(6)"  ::: "memory"); }
      }
      __builtin_amdgcn_sched_barrier(0);
    }
  }

  // ---- EPI2 appendix: fused LN2 over just-written x1 rows ----
  if (EPI == 2) {
    s0 += __shfl_xor(s0, 16); s0 += __shfl_xor(s0, 32);
    q0 += __shfl_xor(q0, 16); q0 += __shfl_xor(q0, 32);
    s1 += __shfl_xor(s1, 16); s1 += __shfl_xor(s1, 32);
    q1 += __shfl_xor(q1, 16); q1 += __shfl_xor(q1, 32);
    float mu0 = s0 * (1.0f / 256.0f);
    float rs0 = rsqrtf(q0 * (1.0f / 256.0f) - mu0 * mu0 + 1e-5f);
    float mu1 = s1 * (1.0f / 256.0f);
    float rs1 = rsqrtf(q1 * (1.0f / 256.0f) - mu1 * mu1 + 1e-5f);
    for (int c = 0; c < NC; ++c) {
      const int cb0 = c * 32 + cl, cb1 = cb0 + 16;
      f32x4 v00 = *(const f32x4*)(Cf + ra0 + cb0);
      f32x4 v01 = *(const f32x4*)(Cf + ra0 + cb1);
      f32x4 v10 = *(const f32x4*)(Cf + ra1 + cb0);
      f32x4 v11 = *(const f32x4*)(Cf + ra1 + cb1);
      f32x4 sa = *(const f32x4*)(ln2s + cb0);
      f32x4 sb = *(const f32x4*)(ln2s + cb1);
      f32x4 ba = *(const f32x4*)(ln2b + cb0);
      f32x4 bb = *(const f32x4*)(ln2b + cb1);
      union { bf16 h[4]; uint2 u; } p00, p01, p10, p11;
      #pragma unroll
      for (int j = 0; j < 4; ++j) {
        p00.h[j] = __float2bfloat16((v00[j] - mu0) * rs0 * sa[j] + ba[j]);
        p01.h[j] = __float2bfloat16((v01[j] - mu0) * rs0 * sb[j] + bb[j]);
        p10.h[j] = __float2bfloat16((v10[j] - mu1) * rs1 * sa[j] + ba[j]);
        p11.h[j] = __float2bfloat16((v11[j] - mu1) * rs1 * sb[j] + bb[j]);
      }
      *(uint2*)(scr + l15 * 80 + lh * 8)             = p00.u;
      *(uint2*)(scr + l15 * 80 + 32 + lh * 8)        = p01.u;
      *(uint2*)(scr + (16 + l15) * 80 + lh * 8)      = p10.u;
      *(uint2*)(scr + (16 + l15) * 80 + 32 + lh * 8) = p11.u;
      uint4 r0 = *(const uint4*)(scr + (lane >> 2) * 80 + (lane & 3) * 16);
      uint4 r1 = *(const uint4*)(scr + (16 + (lane >> 2)) * 80 + (lane & 3) * 16);
      const int cbs = c * 32 + (lane & 3) * 8;
      *(uint4*)(ln2out + rbA + cbs) = r0;
      *(uint4*)(ln2out + rbB + cbs) = r1;
    }
  }
}

// ============ MLP2 pipelined GEMM: x1 += act @ W2^T + b2 (K=1024, N=256) ============
__global__ __launch_bounds__(256, 2) void k_pipe_bt(
    const bf16* __restrict__ A, const bf16* __restrict__ Bw,
    const float* __restrict__ bias, float* __restrict__ Cf)
{
  __shared__ __align__(16) char lds[73728];   // 3 x (8KB A + 16KB B)

  const int tid = threadIdx.x;
  const int wid = tid >> 6;
  const int lane = tid & 63;
  const int l15 = lane & 15, lh = lane >> 4;
  const int wr = (wid >> 1) * 64;
  const int wc = (wid & 1) * 128;
  const int rowBase = blockIdx.x * 128;

  auto stage = [&](int t) {   // 6 vmem ops/thread
    char* dA = lds + (t % 3) * 24576;
    char* dB = dA + 8192;
    #pragma unroll
    for (int i = 0; i < 2; ++i) {
      int off = (i * 256 + tid) * 16;
      int r = off >> 6, cb = off & 63;
      int csw = cb ^ ((r & 3) << 4);
      gload_lds16((const char*)(A + (size_t)(rowBase + r) * 1024 + t * 32) + csw, dA + off);
    }
    #pragma unroll
    for (int i = 0; i < 4; ++i) {
      int off = (i * 256 + tid) * 16;
      int r = off >> 6, cb = off & 63;
      int csw = cb ^ ((r & 3) << 4);
      gload_lds16((const char*)(Bw + (size_t)r * 1024 + t * 32) + csw, dB + off);
    }
  };

  f32x4 acc[4][8];
  #pragma unroll
  for (int m = 0; m < 4; ++m)
    #pragma unroll
    for (int n = 0; n < 8; ++n) acc[m][n] = (f32x4){0.f,0.f,0.f,0.f};

  stage(0);
  stage(1);
  asm volatile("s_waitcnt vmcnt(6)" ::: "memory");
  __builtin_amdgcn_sched_barrier(0);

  for (int t = 0; t < 32; ++t) {
    __builtin_amdgcn_s_barrier();
    __builtin_amdgcn_sched_barrier(0);

    if (t + 2 < 32) stage(t + 2);

    const char* bufA = lds + (t % 3) * 24576;
    const char* bufB = bufA + 8192;
    bf16x8 af[4], bfr[8];
    #pragma unroll
    for (int m = 0; m < 4; ++m) {
      int rA = wr + m * 16 + l15;
      af[m] = *(const bf16x8*)(bufA + rA * 64 + ((lh * 16) ^ ((rA & 3) << 4)));
    }
    #pragma unroll
    for (int n = 0; n < 8; ++n) {
      int rB = wc + n * 16 + l15;
      bfr[n] = *(const bf16x8*)(bufB + rB * 64 + ((lh * 16) ^ ((rB & 3) << 4)));
    }
    #pragma unroll
    for (int m = 0; m < 4; ++m)
      #pragma unroll
      for (int n = 0; n < 8; ++n)
        acc[m][n] = __builtin_amdgcn_mfma_f32_16x16x32_bf16(bfr[n], af[m], acc[m][n], 0, 0, 0);

    if (t + 2 < 32) { asm volatile("s_waitcnt vmcnt(6)" ::: "memory"); }
    else if (t < 31) { asm volatile("s_waitcnt vmcnt(0)" ::: "memory"); }
    __builtin_amdgcn_sched_barrier(0);
  }

  #pragma unroll
  for (int m = 0; m < 4; ++m) {
    size_t rowAddr = (size_t)(rowBase + wr + m * 16 + l15) * 256;
    #pragma unroll
    for (int n = 0; n < 8; ++n) {
      const int colb = wc + n * 16 + lh * 4;
      const f32x4 b4 = *(const f32x4*)(bias + colb);
      f32x4* p = (f32x4*)(Cf + rowAddr + colb);
      f32x4 cc = *p;
      #pragma unroll
      for (int j = 0; j < 4; ++j) cc[j] += acc[m][n][j] + b4[j];
      *p = cc;
    }
  }
}

// ---------------- attention: 1 wave per (window, head) ----------------
__global__ __launch_bounds__(256) void k_attn(
    const bf16* __restrict__ qkv, const float* __restrict__ btab,
    bf16* __restrict__ outp)
{
  __shared__ __align__(16) char smem[71680];
  float* sb = (float*)smem;
  const int tid = threadIdx.x, wid = tid >> 6, lane = tid & 63;
  const int l15 = lane & 15, lh = lane >> 4;
  const int h = blockIdx.x >> 8;
  const int win = ((blockIdx.x & 255) << 2) + wid;
  const int tb = win << 6;
  char* plw = smem + 16384 + wid * 9216;
  char* vtw = smem + 16384 + 36864 + wid * 4608;

  for (int i = tid; i < 4096; i += 256) sb[i] = btab[(h << 12) + i];
  __syncthreads();

  bf16x8 qf[4], kf[4];
  #pragma unroll
  for (int m = 0; m < 4; ++m) {
    size_t base = (size_t)(tb + m * 16 + l15) * 768 + h * 32 + lh * 8;
    qf[m] = *(const bf16x8*)(qkv + base);
    kf[m] = *(const bf16x8*)(qkv + base + 256);
  }
  f32x4 s[4][4];
  #pragma unroll
  for (int i = 0; i < 4; ++i)
    #pragma unroll
    for (int j = 0; j < 4; ++j) {
      s[i][j] = (f32x4){0.f,0.f,0.f,0.f};
      s[i][j] = __builtin_amdgcn_mfma_f32_16x16x32_bf16(qf[i], kf[j], s[i][j], 0, 0, 0);
    }

  #pragma unroll
  for (int it = 0; it < 32; ++it) {
    int idx = it * 64 + lane;
    int m = idx >> 5, d = idx & 31;
    bf16 vv = qkv[(size_t)(tb + m) * 768 + 512 + h * 32 + d];
    *(bf16*)(vtw + d * 144 + m * 2) = vv;
  }

  int ww = win & 63, wi = ww >> 3, wj = ww & 7;
  int labm[4];
  #pragma unroll
  for (int jf = 0; jf < 4; ++jf) {
    int m = jf * 16 + l15;
    int yy = wi * 8 + (m >> 3), xx = wj * 8 + (m & 7);
    labm[jf] = (yy < 56 ? 0 : (yy < 60 ? 1 : 2)) * 3 + (xx < 56 ? 0 : (xx < 60 ? 1 : 2));
  }
  float rsum[4][4];
  const float scale = 0.17677669529663687f;
  #pragma unroll
  for (int i = 0; i < 4; ++i) {
    #pragma unroll
    for (int j = 0; j < 4; ++j) {
      int n = i * 16 + lh * 4 + j;
      int yy = wi * 8 + (n >> 3), xx = wj * 8 + (n & 7);
      int labn = (yy < 56 ? 0 : (yy < 60 ? 1 : 2)) * 3 + (xx < 56 ? 0 : (xx < 60 ? 1 : 2));
      float vals[4]; float mx = -1e30f;
      #pragma unroll
      for (int jf = 0; jf < 4; ++jf) {
        int m = jf * 16 + l15;
        float v = s[i][jf][j] * scale + sb[(n << 6) + m];
        if (labn != labm[jf]) v -= 100.0f;
        vals[jf] = v; mx = fmaxf(mx, v);
      }
      #pragma unroll
      for (int o = 1; o < 16; o <<= 1) mx = fmaxf(mx, __shfl_xor(mx, o));
      float sum = 0.0f;
      #pragma unroll
      for (int jf = 0; jf < 4; ++jf) {
        float e = __expf(vals[jf] - mx);
        sum += e;
        *(bf16*)(plw + n * 144 + (jf * 16 + l15) * 2) = __float2bfloat16(e);
      }
      #pragma unroll
      for (int o = 1; o < 16; o <<= 1) sum += __shfl_xor(sum, o);
      rsum[i][j] = sum;
    }
  }
  __syncthreads();

  f32x4 o[4][2];
  #pragma unroll
  for (int i = 0; i < 4; ++i) { o[i][0] = (f32x4){0.f,0.f,0.f,0.f}; o[i][1] = (f32x4){0.f,0.f,0.f,0.f}; }
  #pragma unroll
  for (int kk = 0; kk < 2; ++kk) {
    bf16x8 pf[4], vf[2];
    #pragma unroll
    for (int i = 0; i < 4; ++i)
      pf[i] = *(const bf16x8*)(plw + (i * 16 + l15) * 144 + kk * 64 + lh * 16);
    #pragma unroll
    for (int df = 0; df < 2; ++df)
      vf[df] = *(const bf16x8*)(vtw + (df * 16 + l15) * 144 + kk * 64 + lh * 16);
    #pragma unroll
    for (int i = 0; i < 4; ++i)
      #pragma unroll
      for (int df = 0; df < 2; ++df)
        o[i][df] = __builtin_amdgcn_mfma_f32_16x16x32_bf16(pf[i], vf[df], o[i][df], 0, 0, 0);
  }
  #pragma unroll
  for (int i = 0; i < 4; ++i)
    #pragma unroll
    for (int df = 0; df < 2; ++df)
      #pragma unroll
      for (int j = 0; j < 4; ++j) {
        int n = i * 16 + lh * 4 + j;
        int d = df * 16 + l15;
        float v = o[i][df][j] / rsum[i][j];
        outp[(size_t)(tb + n) * 256 + h * 32 + d] = __float2bfloat16(v);
      }
}

// ---------------- launch ----------------
extern "C" void kernel_launch(void* const* d_in, const int* in_sizes, int n_in,
                              void* d_out, int out_size, void* d_ws, size_t ws_size,
                              hipStream_t stream) {
  (void)in_sizes; (void)n_in; (void)out_size; (void)ws_size;
  const float* x      = (const float*)d_in[0];
  const float* ln1_s  = (const float*)d_in[1];
  const float* ln1_b  = (const float*)d_in[2];
  const float* qkv_w  = (const float*)d_in[3];
  const float* qkv_b  = (const float*)d_in[4];
  const float* proj_w = (const float*)d_in[5];
  const float* proj_b = (const float*)d_in[6];
  const float* rel_b  = (const float*)d_in[7];
  const float* ln2_s  = (const float*)d_in[8];
  const float* ln2_b  = (const float*)d_in[9];
  const float* w1     = (const float*)d_in[10];
  const float* b1     = (const float*)d_in[11];
  const float* w2     = (const float*)d_in[12];
  const float* b2     = (const float*)d_in[13];

  char* ws = (char*)d_ws;
  bf16*  wqkv  = (bf16*)(ws + 0);               // 196608 el
  bf16*  wproj = wqkv + 196608;                 // 65536 el
  bf16*  wm1   = wqkv + 262144;                 // 262144 el
  bf16*  wm2   = wqkv + 524288;                 // 262144 el
  float* btab  = (float*)(ws + 1572864);        // 32768 f32
  bf16*  hbuf  = (bf16*)(ws + 2097152);         // 65536x256
  bf16*  qkvb  = (bf16*)(ws + 35651584);        // 65536x768
  bf16*  attnb = (bf16*)(ws + 136314880);       // 65536x256
  bf16*  ln2buf = hbuf;                         // reuse (h dead after QKV gemm)
  bf16*  actb  = qkvb;                          // reuse (qkv/attn dead after proj)
  float* x1    = (float*)d_out;                 // residual lives in d_out

  k_conv_weights<<<3072, 256, 0, stream>>>(qkv_w, proj_w, w1, w2, wqkv);
  k_build_btab<<<128, 256, 0, stream>>>(rel_b, btab);
  k_ln1_window<<<16384, 256, 0, stream>>>(x, ln1_s, ln1_b, hbuf);
  k_pipe_ar<0><<<512, 256, 0, stream>>>(hbuf, wqkv, qkv_b, nullptr, qkvb, nullptr,
                                        nullptr, nullptr, nullptr, 768);
  k_attn<<<2048, 256, 0, stream>>>(qkvb, btab, attnb);
  k_pipe_ar<2><<<512, 256, 0, stream>>>(attnb, wproj, proj_b, x1, nullptr, x,
                                        ln2_s, ln2_b, ln2buf, 256);
  k_pipe_ar<1><<<512, 256, 0, stream>>>(ln2buf, wm1, b1, nullptr, actb, nullptr,
                                        nullptr, nullptr, nullptr, 1024);
  k_pipe_bt<<<512, 256, 0, stream>>>(actb, wm2, b2, x1);
}

// Round 10
// 275.546 us; speedup vs baseline: 2.5304x; 1.1230x over previous
//
#include <hip/hip_runtime.h>
#include <hip/hip_bf16.h>
#include <math.h>

#define AS1 __attribute__((address_space(1)))
#define AS3 __attribute__((address_space(3)))

typedef __bf16  bf16x8 __attribute__((ext_vector_type(8)));
typedef float   f32x4  __attribute__((ext_vector_type(4)));
typedef __hip_bfloat16 bf16;

__device__ __forceinline__ void gload_lds16(const void* g, void* l) {
  __builtin_amdgcn_global_load_lds((const AS1 void*)g, (AS3 void*)l, 16, 0, 0);
}

// ---------------- weight conversion f32 -> bf16 ----------------
__global__ __launch_bounds__(256) void k_conv_weights(
    const float* __restrict__ qkvw, const float* __restrict__ projw,
    const float* __restrict__ w1, const float* __restrict__ w2,
    bf16* __restrict__ dst)
{
  int i = blockIdx.x * 256 + threadIdx.x;   // grid covers exactly 786432
  float v;
  if (i < 196608)       v = qkvw[i];
  else if (i < 262144)  v = projw[i - 196608];
  else if (i < 524288)  v = w1[i - 262144];
  else                  v = w2[i - 524288];
  dst[i] = __float2bfloat16(v);
}

// ---------------- rel-pos bias table: btab[h][n][m] ----------------
__global__ __launch_bounds__(256) void k_build_btab(
    const float* __restrict__ rel_bias, float* __restrict__ btab)
{
  int i = blockIdx.x * 256 + threadIdx.x;   // 32768
  int h = i >> 12, r = i & 4095, n = r >> 6, m = r & 63;
  int idx = ((n >> 3) - (m >> 3) + 7) * 15 + ((n & 7) - (m & 7) + 7);
  btab[i] = rel_bias[idx * 8 + h];
}

// ---------------- LN1 + roll(-4,-4) + window partition, f32 -> bf16 ----------------
__global__ __launch_bounds__(256) void k_ln1_window(
    const float* __restrict__ x, const float* __restrict__ sc,
    const float* __restrict__ bi, bf16* __restrict__ hout)
{
  int t = blockIdx.x * 4 + (threadIdx.x >> 6);
  int lane = threadIdx.x & 63;
  int win = t >> 6, nn = t & 63;
  int b = win >> 6, ww = win & 63;
  int ry = ((ww >> 3) << 3) + (nn >> 3);
  int rx = ((ww & 7) << 3) + (nn & 7);
  int sy = (ry + 4) & 63, sx = (rx + 4) & 63;
  const float* src = x + ((size_t)(((b << 6) + sy) << 6) + sx) * 256;
  f32x4 v = *(const f32x4*)(src + lane * 4);
  float s = v[0] + v[1] + v[2] + v[3];
  #pragma unroll
  for (int o = 1; o < 64; o <<= 1) s += __shfl_xor(s, o);
  float mu = s * (1.0f / 256.0f);
  float d0 = v[0]-mu, d1 = v[1]-mu, d2 = v[2]-mu, d3 = v[3]-mu;
  float q = d0*d0 + d1*d1 + d2*d2 + d3*d3;
  #pragma unroll
  for (int o = 1; o < 64; o <<= 1) q += __shfl_xor(q, o);
  float rstd = rsqrtf(q * (1.0f / 256.0f) + 1e-5f);
  int c = lane * 4;
  union { bf16 h[4]; uint2 u; } pk;
  pk.h[0] = __float2bfloat16(d0 * rstd * sc[c+0] + bi[c+0]);
  pk.h[1] = __float2bfloat16(d1 * rstd * sc[c+1] + bi[c+1]);
  pk.h[2] = __float2bfloat16(d2 * rstd * sc[c+2] + bi[c+2]);
  pk.h[3] = __float2bfloat16(d3 * rstd * sc[c+3] + bi[c+3]);
  *(uint2*)(hout + (size_t)t * 256 + c) = pk.u;
}

// ============ A-resident N-streaming GEMM (K=256), depth-4 ring, exact vmcnt ============
// EPI 0: bf16 (bounce store) | EPI 2: proj remap + resid f32 + FUSED LN2 -> bf16
template<int EPI>
__global__ __launch_bounds__(256, 2) void k_pipe_ar(
    const bf16* __restrict__ A, const bf16* __restrict__ Bw,
    const float* __restrict__ bias,
    float* __restrict__ Cf, bf16* __restrict__ Cb,
    const float* __restrict__ resid,
    const float* __restrict__ ln2s, const float* __restrict__ ln2b,
    bf16* __restrict__ ln2out, int N)
{
  __shared__ __align__(16) char lds[65536 + 10240];   // 4x16KB ring + 4x2560B bounce

  const int tid = threadIdx.x;
  const int wid = tid >> 6;
  const int lane = tid & 63;
  const int l15 = lane & 15, lh = lane >> 4;
  const int rowBase = blockIdx.x * 128 + wid * 32;
  const int NC = N >> 5;
  char* scr = lds + 65536 + wid * 2560;   // 32 rows x 80B

  auto stage = [&](int c) {   // 4 vmem ops/thread
    char* dst = lds + (c & 3) * 16384;
    const char* srcB = (const char*)Bw + (size_t)c * 32 * 512;
    #pragma unroll
    for (int i = 0; i < 4; ++i) {
      int off = (i * 256 + tid) * 16;
      int r = off >> 9, cb = off & 511;
      int csw = cb ^ ((r & 7) << 4);
      gload_lds16(srcB + (size_t)r * 512 + csw, dst + off);
    }
  };

  bf16x8 af[2][8];
  {
    const bf16* a0 = A + (size_t)(rowBase + l15) * 256 + lh * 8;
    #pragma unroll
    for (int kk = 0; kk < 8; ++kk) {
      af[0][kk] = *(const bf16x8*)(a0 + kk * 32);
      af[1][kk] = *(const bf16x8*)(a0 + 4096 + kk * 32);
    }
  }

  auto remap = [&](int row) -> size_t {
    int win = row >> 6, nn = row & 63;
    int b = win >> 6, ww = win & 63;
    int ry = ((ww >> 3) << 3) + (nn >> 3);
    int rx = ((ww & 7) << 3) + (nn & 7);
    int fy = (ry + 4) & 63, fx = (rx + 4) & 63;
    return ((size_t)(((b << 6) + fy) << 6) + fx) * 256;
  };
  size_t ra0 = 0, ra1 = 0;
  size_t rbA, rbB;
  if (EPI == 2) {
    ra0 = remap(rowBase + l15);
    ra1 = remap(rowBase + 16 + l15);
    rbA = remap(rowBase + (lane >> 2));
    rbB = remap(rowBase + 16 + (lane >> 2));
  } else {
    rbA = (size_t)(rowBase + (lane >> 2)) * N;
    rbB = rbA + (size_t)16 * N;
  }

  const int cl = lh * 4;
  f32x4 bc0 = *(const f32x4*)(bias + cl);
  f32x4 bc1 = *(const f32x4*)(bias + cl + 16);
  f32x4 rc00, rc10, rc01, rc11;
  if (EPI == 2) {
    rc00 = *(const f32x4*)(resid + ra0 + cl);
    rc10 = *(const f32x4*)(resid + ra1 + cl);
    rc01 = *(const f32x4*)(resid + ra0 + cl + 16);
    rc11 = *(const f32x4*)(resid + ra1 + cl + 16);
  }
  stage(0); stage(1); stage(2);
  asm volatile("s_waitcnt vmcnt(8)" ::: "memory");   // stage(0) done
  __builtin_amdgcn_sched_barrier(0);

  float s0 = 0.f, q0 = 0.f, s1 = 0.f, q1 = 0.f;

  for (int c = 0; c < NC; ++c) {
    __builtin_amdgcn_s_barrier();
    __builtin_amdgcn_sched_barrier(0);

    f32x4 bn0, bn1, rn00, rn10, rn01, rn11;
    if (c + 1 < NC) {
      const int ncl = (c + 1) * 32 + cl;
      bn0 = *(const f32x4*)(bias + ncl);
      bn1 = *(const f32x4*)(bias + ncl + 16);
      if (EPI == 2) {
        rn00 = *(const f32x4*)(resid + ra0 + ncl);
        rn10 = *(const f32x4*)(resid + ra1 + ncl);
        rn01 = *(const f32x4*)(resid + ra0 + ncl + 16);
        rn11 = *(const f32x4*)(resid + ra1 + ncl + 16);
      }
    }
    if (c + 3 < NC) stage(c + 3);

    const char* buf = lds + (c & 3) * 16384;
    const int xr = (l15 & 7) << 4;
    const int base0 = l15 * 512;
    f32x4 a00 = (f32x4){0.f,0.f,0.f,0.f};
    f32x4 a10 = (f32x4){0.f,0.f,0.f,0.f};
    f32x4 a01 = (f32x4){0.f,0.f,0.f,0.f};
    f32x4 a11 = (f32x4){0.f,0.f,0.f,0.f};
    #pragma unroll
    for (int kk = 0; kk < 8; ++kk) {
      const int ko = (kk * 64 + lh * 16) ^ xr;
      bf16x8 b0 = *(const bf16x8*)(buf + base0 + ko);
      bf16x8 b1 = *(const bf16x8*)(buf + base0 + 8192 + ko);
      a00 = __builtin_amdgcn_mfma_f32_16x16x32_bf16(b0, af[0][kk], a00, 0, 0, 0);
      a10 = __builtin_amdgcn_mfma_f32_16x16x32_bf16(b0, af[1][kk], a10, 0, 0, 0);
      a01 = __builtin_amdgcn_mfma_f32_16x16x32_bf16(b1, af[0][kk], a01, 0, 0, 0);
      a11 = __builtin_amdgcn_mfma_f32_16x16x32_bf16(b1, af[1][kk], a11, 0, 0, 0);
    }

    const int cbs = c * 32 + (lane & 3) * 8;
    if (EPI == 0) {
      union { bf16 h[4]; uint2 u; } p00, p01, p10, p11;
      #pragma unroll
      for (int j = 0; j < 4; ++j) {
        p00.h[j] = __float2bfloat16(a00[j] + bc0[j]);
        p01.h[j] = __float2bfloat16(a01[j] + bc1[j]);
        p10.h[j] = __float2bfloat16(a10[j] + bc0[j]);
        p11.h[j] = __float2bfloat16(a11[j] + bc1[j]);
      }
      *(uint2*)(scr + l15 * 80 + lh * 8)            = p00.u;
      *(uint2*)(scr + l15 * 80 + 32 + lh * 8)       = p01.u;
      *(uint2*)(scr + (16 + l15) * 80 + lh * 8)     = p10.u;
      *(uint2*)(scr + (16 + l15) * 80 + 32 + lh * 8)= p11.u;
      uint4 r0 = *(const uint4*)(scr + (lane >> 2) * 80 + (lane & 3) * 16);
      uint4 r1 = *(const uint4*)(scr + (16 + (lane >> 2)) * 80 + (lane & 3) * 16);
      *(uint4*)(Cb + rbA + cbs) = r0;
      *(uint4*)(Cb + rbB + cbs) = r1;
    } else {
      const int colb0 = c * 32 + cl, colb1 = colb0 + 16;
      f32x4 o00, o10, o01, o11;
      #pragma unroll
      for (int j = 0; j < 4; ++j) {
        o00[j] = a00[j] + bc0[j] + rc00[j];
        o10[j] = a10[j] + bc0[j] + rc10[j];
        o01[j] = a01[j] + bc1[j] + rc01[j];
        o11[j] = a11[j] + bc1[j] + rc11[j];
      }
      *(f32x4*)(Cf + ra0 + colb0) = o00;
      *(f32x4*)(Cf + ra1 + colb0) = o10;
      *(f32x4*)(Cf + ra0 + colb1) = o01;
      *(f32x4*)(Cf + ra1 + colb1) = o11;
      #pragma unroll
      for (int j = 0; j < 4; ++j) {
        s0 += o00[j] + o01[j];  q0 += o00[j]*o00[j] + o01[j]*o01[j];
        s1 += o10[j] + o11[j];  q1 += o10[j]*o10[j] + o11[j]*o11[j];
      }
    }

    if (c + 1 < NC) {
      bc0 = bn0; bc1 = bn1;
      if (EPI == 2) { rc00 = rn00; rc10 = rn10; rc01 = rn01; rc11 = rn11; }
    }

    if (c + 1 < NC) {
      if (EPI == 2) {
        if (c == 0)            { asm volatile("s_waitcnt vmcnt(18)" ::: "memory"); }
        else if (c + 3 < NC)   { asm volatile("s_waitcnt vmcnt(28)" ::: "memory"); }
        else                   { asm volatile("s_waitcnt vmcnt(6)"  ::: "memory"); }
      } else {
        if (c == 0)            { asm volatile("s_waitcnt vmcnt(12)" ::: "memory"); }
        else if (c + 3 < NC)   { asm volatile("s_waitcnt vmcnt(16)" ::: "memory"); }
        else                   { asm volatile("s_waitcnt vmcnt(6)"  ::: "memory"); }
      }
      __builtin_amdgcn_sched_barrier(0);
    }
  }

  if (EPI == 2) {
    s0 += __shfl_xor(s0, 16); s0 += __shfl_xor(s0, 32);
    q0 += __shfl_xor(q0, 16); q0 += __shfl_xor(q0, 32);
    s1 += __shfl_xor(s1, 16); s1 += __shfl_xor(s1, 32);
    q1 += __shfl_xor(q1, 16); q1 += __shfl_xor(q1, 32);
    float mu0 = s0 * (1.0f / 256.0f);
    float rs0 = rsqrtf(q0 * (1.0f / 256.0f) - mu0 * mu0 + 1e-5f);
    float mu1 = s1 * (1.0f / 256.0f);
    float rs1 = rsqrtf(q1 * (1.0f / 256.0f) - mu1 * mu1 + 1e-5f);
    for (int c = 0; c < NC; ++c) {
      const int cb0 = c * 32 + cl, cb1 = cb0 + 16;
      f32x4 v00 = *(const f32x4*)(Cf + ra0 + cb0);
      f32x4 v01 = *(const f32x4*)(Cf + ra0 + cb1);
      f32x4 v10 = *(const f32x4*)(Cf + ra1 + cb0);
      f32x4 v11 = *(const f32x4*)(Cf + ra1 + cb1);
      f32x4 sa = *(const f32x4*)(ln2s + cb0);
      f32x4 sb = *(const f32x4*)(ln2s + cb1);
      f32x4 ba = *(const f32x4*)(ln2b + cb0);
      f32x4 bb = *(const f32x4*)(ln2b + cb1);
      union { bf16 h[4]; uint2 u; } p00, p01, p10, p11;
      #pragma unroll
      for (int j = 0; j < 4; ++j) {
        p00.h[j] = __float2bfloat16((v00[j] - mu0) * rs0 * sa[j] + ba[j]);
        p01.h[j] = __float2bfloat16((v01[j] - mu0) * rs0 * sb[j] + bb[j]);
        p10.h[j] = __float2bfloat16((v10[j] - mu1) * rs1 * sa[j] + ba[j]);
        p11.h[j] = __float2bfloat16((v11[j] - mu1) * rs1 * sb[j] + bb[j]);
      }
      *(uint2*)(scr + l15 * 80 + lh * 8)             = p00.u;
      *(uint2*)(scr + l15 * 80 + 32 + lh * 8)        = p01.u;
      *(uint2*)(scr + (16 + l15) * 80 + lh * 8)      = p10.u;
      *(uint2*)(scr + (16 + l15) * 80 + 32 + lh * 8) = p11.u;
      uint4 r0 = *(const uint4*)(scr + (lane >> 2) * 80 + (lane & 3) * 16);
      uint4 r1 = *(const uint4*)(scr + (16 + (lane >> 2)) * 80 + (lane & 3) * 16);
      const int cbs = c * 32 + (lane & 3) * 8;
      *(uint4*)(ln2out + rbA + cbs) = r0;
      *(uint4*)(ln2out + rbB + cbs) = r1;
    }
  }
}

// ============ FUSED MLP: x1 += GELU(ln2h @ W1^T + b1) @ W2^T + b2 ============
// Block 128 rows (4 waves x 32); af[2][8] ln2h resident. Stream 32 hidden-chunks:
// depth-2 ring of {W1-chunk 16KB | W2-chunk 16KB}; acc1 = A@W1^T (32 MFMA) ->
// GELU (b1 from LDS) -> bounce to bf16 B-fragment layout -> acc2[2][16] +=
// mfma(w2f, actf) (32 MFMA). Persistent acc2 (128 VGPR); single f32 RMW epilogue.
// No global stores in the loop => end-of-iter vmcnt(0) waits only stage(c+1).
__global__ __launch_bounds__(256, 2) void k_mlp(
    const bf16* __restrict__ A, const bf16* __restrict__ W1,
    const float* __restrict__ B1, const bf16* __restrict__ W2,
    const float* __restrict__ B2, float* __restrict__ X1)
{
  __shared__ __align__(16) char lds[79872];  // 2x32KB ring | 4x2560B bounce | 4KB b1

  const int tid = threadIdx.x;
  const int wid = tid >> 6;
  const int lane = tid & 63;
  const int l15 = lane & 15, lh = lane >> 4;
  const int rowBase = blockIdx.x * 128 + wid * 32;
  char* scr   = lds + 65536 + wid * 2560;
  char* b1lds = lds + 75776;

  auto stage = [&](int c) {   // 8 vmem ops/thread (W1 4 + W2 4)
    char* slot = lds + (c & 1) * 32768;
    const char* srcW1 = (const char*)W1 + (size_t)c * 32 * 512;
    #pragma unroll
    for (int i = 0; i < 4; ++i) {
      int off = (i * 256 + tid) * 16;
      int r = off >> 9, cb = off & 511;
      int csw = cb ^ ((r & 7) << 4);
      gload_lds16(srcW1 + (size_t)r * 512 + csw, slot + off);
    }
    // W2 chunk: LDS layout [k16-chunk][256 rows x 16B]
    #pragma unroll
    for (int i = 0; i < 4; ++i) {
      int off = (i * 256 + tid) * 16;
      int ch = off >> 12, row = (off >> 4) & 255;
      gload_lds16((const char*)W2 + (size_t)row * 2048 + (size_t)c * 64 + ch * 16,
                  slot + 16384 + off);
    }
  };

  // prologue: b1 -> LDS, A fragments, stage(0)
  gload_lds16((const char*)B1 + tid * 16, b1lds + tid * 16);
  bf16x8 af[2][8];
  {
    const bf16* a0 = A + (size_t)(rowBase + l15) * 256 + lh * 8;
    #pragma unroll
    for (int kk = 0; kk < 8; ++kk) {
      af[0][kk] = *(const bf16x8*)(a0 + kk * 32);
      af[1][kk] = *(const bf16x8*)(a0 + 4096 + kk * 32);
    }
  }
  stage(0);
  asm volatile("s_waitcnt vmcnt(0)" ::: "memory");
  __builtin_amdgcn_sched_barrier(0);

  f32x4 acc2[2][16];
  #pragma unroll
  for (int m = 0; m < 2; ++m)
    #pragma unroll
    for (int n = 0; n < 16; ++n) acc2[m][n] = (f32x4){0.f,0.f,0.f,0.f};

  for (int c = 0; c < 32; ++c) {
    __builtin_amdgcn_s_barrier();                 // stage(c) visible to all waves
    __builtin_amdgcn_sched_barrier(0);

    if (c + 1 < 32) stage(c + 1);

    // ---- stage 1: acc1 = A @ W1chunk^T (32 MFMA) ----
    const char* slot = lds + (c & 1) * 32768;
    const int xr = (l15 & 7) << 4;
    const int base0 = l15 * 512;
    f32x4 a00 = (f32x4){0.f,0.f,0.f,0.f};
    f32x4 a10 = (f32x4){0.f,0.f,0.f,0.f};
    f32x4 a01 = (f32x4){0.f,0.f,0.f,0.f};
    f32x4 a11 = (f32x4){0.f,0.f,0.f,0.f};
    #pragma unroll
    for (int kk = 0; kk < 8; ++kk) {
      const int ko = (kk * 64 + lh * 16) ^ xr;
      bf16x8 b0 = *(const bf16x8*)(slot + base0 + ko);
      bf16x8 b1 = *(const bf16x8*)(slot + base0 + 8192 + ko);
      a00 = __builtin_amdgcn_mfma_f32_16x16x32_bf16(b0, af[0][kk], a00, 0, 0, 0);
      a10 = __builtin_amdgcn_mfma_f32_16x16x32_bf16(b0, af[1][kk], a10, 0, 0, 0);
      a01 = __builtin_amdgcn_mfma_f32_16x16x32_bf16(b1, af[0][kk], a01, 0, 0, 0);
      a11 = __builtin_amdgcn_mfma_f32_16x16x32_bf16(b1, af[1][kk], a11, 0, 0, 0);
    }

    // ---- GELU + bounce to bf16 act fragments ----
    f32x4 bv0 = *(const f32x4*)(b1lds + c * 128 + lh * 16);
    f32x4 bv1 = *(const f32x4*)(b1lds + c * 128 + 64 + lh * 16);
    auto gelu = [](float v) -> bf16 {
      float w = fmaf(v * v, 0.1029434f, 2.3022083f);   // ln2-folded tanh-GELU
      float e = __builtin_amdgcn_exp2f(-v * w);
      return __float2bfloat16(v * __builtin_amdgcn_rcpf(1.0f + e));
    };
    union { bf16 h[4]; uint2 u; } p00, p01, p10, p11;
    #pragma unroll
    for (int j = 0; j < 4; ++j) {
      p00.h[j] = gelu(a00[j] + bv0[j]);
      p01.h[j] = gelu(a01[j] + bv1[j]);
      p10.h[j] = gelu(a10[j] + bv0[j]);
      p11.h[j] = gelu(a11[j] + bv1[j]);
    }
    *(uint2*)(scr + l15 * 80 + lh * 8)             = p00.u;
    *(uint2*)(scr + l15 * 80 + 32 + lh * 8)        = p01.u;
    *(uint2*)(scr + (16 + l15) * 80 + lh * 8)      = p10.u;
    *(uint2*)(scr + (16 + l15) * 80 + 32 + lh * 8) = p11.u;
    bf16x8 actf0 = *(const bf16x8*)(scr + l15 * 80 + lh * 16);
    bf16x8 actf1 = *(const bf16x8*)(scr + (16 + l15) * 80 + lh * 16);

    // ---- stage 2: acc2 += act @ W2chunk^T (32 MFMA) ----
    const char* w2buf = slot + 16384;
    const int w2k = lh * 4096;
    #pragma unroll
    for (int n = 0; n < 16; ++n) {
      bf16x8 wf = *(const bf16x8*)(w2buf + w2k + (n * 16 + l15) * 16);
      acc2[0][n] = __builtin_amdgcn_mfma_f32_16x16x32_bf16(wf, actf0, acc2[0][n], 0, 0, 0);
      acc2[1][n] = __builtin_amdgcn_mfma_f32_16x16x32_bf16(wf, actf1, acc2[1][n], 0, 0, 0);
    }

    if (c + 1 < 32) {
      asm volatile("s_waitcnt vmcnt(0)" ::: "memory");   // stage(c+1) landed
      __builtin_amdgcn_sched_barrier(0);
    }
  }

  // ---- epilogue: x1 += acc2 + b2 (f32 RMW) ----
  #pragma unroll
  for (int m = 0; m < 2; ++m) {
    size_t rowAddr = (size_t)(rowBase + m * 16 + l15) * 256;
    #pragma unroll
    for (int n = 0; n < 16; ++n) {
      const int colb = n * 16 + lh * 4;
      const f32x4 b4 = *(const f32x4*)(B2 + colb);
      f32x4* p = (f32x4*)(X1 + rowAddr + colb);
      f32x4 cc = *p;
      #pragma unroll
      for (int j = 0; j < 4; ++j) cc[j] += acc2[m][n][j] + b4[j];
      *p = cc;
    }
  }
}

// ---------------- attention: 1 wave per (window, head) ----------------
__global__ __launch_bounds__(256) void k_attn(
    const bf16* __restrict__ qkv, const float* __restrict__ btab,
    bf16* __restrict__ outp)
{
  __shared__ __align__(16) char smem[71680];
  float* sb = (float*)smem;
  const int tid = threadIdx.x, wid = tid >> 6, lane = tid & 63;
  const int l15 = lane & 15, lh = lane >> 4;
  const int h = blockIdx.x >> 8;
  const int win = ((blockIdx.x & 255) << 2) + wid;
  const int tb = win << 6;
  char* plw = smem + 16384 + wid * 9216;
  char* vtw = smem + 16384 + 36864 + wid * 4608;

  for (int i = tid; i < 4096; i += 256) sb[i] = btab[(h << 12) + i];
  __syncthreads();

  bf16x8 qf[4], kf[4];
  #pragma unroll
  for (int m = 0; m < 4; ++m) {
    size_t base = (size_t)(tb + m * 16 + l15) * 768 + h * 32 + lh * 8;
    qf[m] = *(const bf16x8*)(qkv + base);
    kf[m] = *(const bf16x8*)(qkv + base + 256);
  }
  f32x4 s[4][4];
  #pragma unroll
  for (int i = 0; i < 4; ++i)
    #pragma unroll
    for (int j = 0; j < 4; ++j) {
      s[i][j] = (f32x4){0.f,0.f,0.f,0.f};
      s[i][j] = __builtin_amdgcn_mfma_f32_16x16x32_bf16(qf[i], kf[j], s[i][j], 0, 0, 0);
    }

  #pragma unroll
  for (int it = 0; it < 32; ++it) {
    int idx = it * 64 + lane;
    int m = idx >> 5, d = idx & 31;
    bf16 vv = qkv[(size_t)(tb + m) * 768 + 512 + h * 32 + d];
    *(bf16*)(vtw + d * 144 + m * 2) = vv;
  }

  int ww = win & 63, wi = ww >> 3, wj = ww & 7;
  int labm[4];
  #pragma unroll
  for (int jf = 0; jf < 4; ++jf) {
    int m = jf * 16 + l15;
    int yy = wi * 8 + (m >> 3), xx = wj * 8 + (m & 7);
    labm[jf] = (yy < 56 ? 0 : (yy < 60 ? 1 : 2)) * 3 + (xx < 56 ? 0 : (xx < 60 ? 1 : 2));
  }
  float rsum[4][4];
  const float scale = 0.17677669529663687f;
  #pragma unroll
  for (int i = 0; i < 4; ++i) {
    #pragma unroll
    for (int j = 0; j < 4; ++j) {
      int n = i * 16 + lh * 4 + j;
      int yy = wi * 8 + (n >> 3), xx = wj * 8 + (n & 7);
      int labn = (yy < 56 ? 0 : (yy < 60 ? 1 : 2)) * 3 + (xx < 56 ? 0 : (xx < 60 ? 1 : 2));
      float vals[4]; float mx = -1e30f;
      #pragma unroll
      for (int jf = 0; jf < 4; ++jf) {
        int m = jf * 16 + l15;
        float v = s[i][jf][j] * scale + sb[(n << 6) + m];
        if (labn != labm[jf]) v -= 100.0f;
        vals[jf] = v; mx = fmaxf(mx, v);
      }
      #pragma unroll
      for (int o = 1; o < 16; o <<= 1) mx = fmaxf(mx, __shfl_xor(mx, o));
      float sum = 0.0f;
      #pragma unroll
      for (int jf = 0; jf < 4; ++jf) {
        float e = __expf(vals[jf] - mx);
        sum += e;
        *(bf16*)(plw + n * 144 + (jf * 16 + l15) * 2) = __float2bfloat16(e);
      }
      #pragma unroll
      for (int o = 1; o < 16; o <<= 1) sum += __shfl_xor(sum, o);
      rsum[i][j] = sum;
    }
  }
  __syncthreads();

  f32x4 o[4][2];
  #pragma unroll
  for (int i = 0; i < 4; ++i) { o[i][0] = (f32x4){0.f,0.f,0.f,0.f}; o[i][1] = (f32x4){0.f,0.f,0.f,0.f}; }
  #pragma unroll
  for (int kk = 0; kk < 2; ++kk) {
    bf16x8 pf[4], vf[2];
    #pragma unroll
    for (int i = 0; i < 4; ++i)
      pf[i] = *(const bf16x8*)(plw + (i * 16 + l15) * 144 + kk * 64 + lh * 16);
    #pragma unroll
    for (int df = 0; df < 2; ++df)
      vf[df] = *(const bf16x8*)(vtw + (df * 16 + l15) * 144 + kk * 64 + lh * 16);
    #pragma unroll
    for (int i = 0; i < 4; ++i)
      #pragma unroll
      for (int df = 0; df < 2; ++df)
        o[i][df] = __builtin_amdgcn_mfma_f32_16x16x32_bf16(pf[i], vf[df], o[i][df], 0, 0, 0);
  }
  #pragma unroll
  for (int i = 0; i < 4; ++i)
    #pragma unroll
    for (int df = 0; df < 2; ++df)
      #pragma unroll
      for (int j = 0; j < 4; ++j) {
        int n = i * 16 + lh * 4 + j;
        int d = df * 16 + l15;
        float v = o[i][df][j] / rsum[i][j];
        outp[(size_t)(tb + n) * 256 + h * 32 + d] = __float2bfloat16(v);
      }
}

// ---------------- launch ----------------
extern "C" void kernel_launch(void* const* d_in, const int* in_sizes, int n_in,
                              void* d_out, int out_size, void* d_ws, size_t ws_size,
                              hipStream_t stream) {
  (void)in_sizes; (void)n_in; (void)out_size; (void)ws_size;
  const float* x      = (const float*)d_in[0];
  const float* ln1_s  = (const float*)d_in[1];
  const float* ln1_b  = (const float*)d_in[2];
  const float* qkv_w  = (const float*)d_in[3];
  const float* qkv_b  = (const float*)d_in[4];
  const float* proj_w = (const float*)d_in[5];
  const float* proj_b = (const float*)d_in[6];
  const float* rel_b  = (const float*)d_in[7];
  const float* ln2_s  = (const float*)d_in[8];
  const float* ln2_b  = (const float*)d_in[9];
  const float* w1     = (const float*)d_in[10];
  const float* b1     = (const float*)d_in[11];
  const float* w2     = (const float*)d_in[12];
  const float* b2     = (const float*)d_in[13];

  char* ws = (char*)d_ws;
  bf16*  wqkv  = (bf16*)(ws + 0);               // 196608 el
  bf16*  wproj = wqkv + 196608;                 // 65536 el
  bf16*  wm1   = wqkv + 262144;                 // 262144 el
  bf16*  wm2   = wqkv + 524288;                 // 262144 el
  float* btab  = (float*)(ws + 1572864);        // 32768 f32
  bf16*  hbuf  = (bf16*)(ws + 2097152);         // 65536x256
  bf16*  qkvb  = (bf16*)(ws + 35651584);        // 65536x768
  bf16*  attnb = (bf16*)(ws + 136314880);       // 65536x256
  bf16*  ln2buf = hbuf;                         // reuse (h dead after QKV gemm)
  float* x1    = (float*)d_out;                 // residual lives in d_out

  k_conv_weights<<<3072, 256, 0, stream>>>(qkv_w, proj_w, w1, w2, wqkv);
  k_build_btab<<<128, 256, 0, stream>>>(rel_b, btab);
  k_ln1_window<<<16384, 256, 0, stream>>>(x, ln1_s, ln1_b, hbuf);
  k_pipe_ar<0><<<512, 256, 0, stream>>>(hbuf, wqkv, qkv_b, nullptr, qkvb, nullptr,
                                        nullptr, nullptr, nullptr, 768);
  k_attn<<<2048, 256, 0, stream>>>(qkvb, btab, attnb);
  k_pipe_ar<2><<<512, 256, 0, stream>>>(attnb, wproj, proj_b, x1, nullptr, x,
                                        ln2_s, ln2_b, ln2buf, 256);
  k_mlp<<<512, 256, 0, stream>>>(ln2buf, wm1, b1, wm2, b2, x1);
}